// Round 2
// baseline (1085.677 us; speedup 1.0000x reference)
//
#include <hip/hip_runtime.h>
#include <hip/hip_bf16.h>
#include <math.h>

// Problem constants
#define S_ENS 10
#define B_DIM 256
#define SD 16
#define OD 8
#define H_DIM 3200
#define OUT1 512
#define IN_DIM 48
#define M_ROWS (S_ENS * B_DIM)     // 2560
#define TEMP_INV 10.0f

typedef unsigned short u16;
typedef __attribute__((ext_vector_type(8))) short short8;
typedef __attribute__((ext_vector_type(4))) short short4v;   // 8B packed bf16x4
typedef __attribute__((ext_vector_type(4))) float floatx4;

__device__ __forceinline__ float sigmoidf_(float x) { return 1.0f / (1.0f + __expf(-x)); }
__device__ __forceinline__ float fast_tanh(float x) {
    x = fminf(fmaxf(x, -15.f), 15.f);
    float e = __expf(2.f * x);
    return (e - 1.f) / (e + 1.f);
}

// fp32 -> bf16 round-to-nearest-even
__device__ __forceinline__ u16 f2bf(float f) {
    union { float f; unsigned u; } v; v.f = f;
    unsigned u = v.u + 0x7fffu + ((v.u >> 16) & 1u);
    return (u16)(u >> 16);
}
__device__ __forceinline__ float bf2f(u16 h) {
    union { unsigned u; float f; } v; v.u = ((unsigned)h) << 16;
    return v.f;
}

// async global->LDS, 16B per lane. LDS dest: wave-uniform base + lane*16.
__device__ __forceinline__ void gld_lds16(const u16* g, u16* l) {
    __builtin_amdgcn_global_load_lds((const __attribute__((address_space(1))) void*)g,
                                     (__attribute__((address_space(3))) void*)l, 16, 0, 0);
}

// Raw barrier with compiler-level memory fence + sched pin (NO auto vmcnt(0)).
__device__ __forceinline__ void bar_() {
    __builtin_amdgcn_sched_barrier(0);
    asm volatile("" ::: "memory");
    __builtin_amdgcn_s_barrier();
    asm volatile("" ::: "memory");
    __builtin_amdgcn_sched_barrier(0);
}
#define VMCNT4() asm volatile("s_waitcnt vmcnt(4)" ::: "memory")

// ---------------------------------------------------------------------------
// 8-phase pipelined 256x128-tile bf16 MFMA K-loop (BK=64 as 2x K=32 slabs),
// 8 waves (512 thr), counted vmcnt(4) at phases 4/8 only (never 0 in-loop),
// chunk-XOR swizzled LDS (verified conflict-free scheme from prior rounds).
//
// Geometry: block tile 256(M) x 128(N). Wave w: wm=w>>2, wn=w&3.
// Wave output is interleaved across block quadrants: fragment (qm,qn,mi)
// covers rows m_base + qm*128 + wm*64 + mi*16, cols n_base + qn*64 + wn*16.
// Phase (qm,qn) computes one C-quadrant: ALL waves read only LDS A-half qm
// and B-half qn => each half-tile is ds_read in exactly one phase, freeing
// its slot for the staged prefetch 1+ barrier-pairs later (race-free).
//
// Steady state per iteration (tiles t=2i in buf0, t+1 in buf1):
//  ph1: rd A(t)h0+B(t)h0   st A(t+1)h1   ph5: rd A(t+1)h0+B(t+1)h0  st A(t+2)h1
//  ph2: rd B(t)h1          st A(t+2)h0   ph6: rd B(t+1)h1           st A(t+3)h0
//  ph3: rd A(t)h1          st B(t+2)h0   ph7: rd A(t+1)h1           st B(t+3)h0
//  ph4: --                 st B(t+2)h1   ph8: --                    st B(t+3)h1
//  vmcnt(4) at end of ph4 (guards t+1 reads) and ph8 (guards t+2 reads).
//
// K axis concatenates two operand pairs: tiles [0,nts) -> (A0,B0), tiles
// [nts,nt) -> (A1,B1) at k=(tile-nts)*64 (fuses X@Wih + Hp@Whh, K=6400).
// ---------------------------------------------------------------------------
#define RDA(BUF, QM) do {                                                          \
    _Pragma("unroll")                                                              \
    for (int mi_ = 0; mi_ < 4; ++mi_) {                                            \
        af[mi_][0] = *(const short8*)(sA + (((BUF)*2 + (QM))*2 + 0)*4096 + aro[mi_]); \
        af[mi_][1] = *(const short8*)(sA + (((BUF)*2 + (QM))*2 + 1)*4096 + aro[mi_]); \
    } } while (0)

#define RDB(BUF, QN, BS) do {                                                      \
    BS[0] = *(const short8*)(sB + (((BUF)*2 + (QN))*2 + 0)*2048 + bro);            \
    BS[1] = *(const short8*)(sB + (((BUF)*2 + (QN))*2 + 1)*2048 + bro);            \
    } while (0)

#define MMAQ(QM, QN, BS) do {                                                      \
    __builtin_amdgcn_s_setprio(1);                                                 \
    _Pragma("unroll")                                                              \
    for (int mi_ = 0; mi_ < 4; ++mi_) {                                            \
        acc[QM][QN][mi_] = __builtin_amdgcn_mfma_f32_16x16x32_bf16(af[mi_][0], BS[0], acc[QM][QN][mi_], 0, 0, 0); \
        acc[QM][QN][mi_] = __builtin_amdgcn_mfma_f32_16x16x32_bf16(af[mi_][1], BS[1], acc[QM][QN][mi_], 0, 0, 0); \
    }                                                                              \
    __builtin_amdgcn_s_setprio(0); } while (0)

__device__ __forceinline__ void kloop8(
    const u16* __restrict__ A0, const u16* __restrict__ A1,
    const u16* __restrict__ B0, const u16* __restrict__ B1,
    int nts, int nt, int m_base, int n_base,
    u16* sA, u16* sB, floatx4 (&acc)[2][2][4])
{
    const int tid = threadIdx.x;
    const int w = tid >> 6, l = tid & 63;
    const int wm = w >> 2, wn = w & 3;

    // staging lane geometry (pre-swizzled global source, linear LDS dest)
    const int rr = l >> 2, c4 = l & 3;
    const int achn = (c4 ^ ((rr >> 1) & 3)) << 3;                 // elems
    const size_t a_off = (size_t)(w * 16 + rr) * H_DIM + achn;    // A: rows w*16..+15 of half
    const size_t b_off = (size_t)((w & 3) * 16 + rr) * H_DIM + achn; // B: rows (w&3)*16..
    const int bj = w >> 2;                                        // B k-slab per wave

    // fragment ds_read offsets (elems), same verified swizzle
    const int frow = l & 15, fch = l >> 4;
    int aro[4];
    #pragma unroll
    for (int mi = 0; mi < 4; ++mi) {
        int r = wm * 64 + mi * 16 + frow;
        aro[mi] = r * 32 + ((fch ^ ((r >> 1) & 3)) << 3);
    }
    int bro;
    { int r = wn * 16 + frow; bro = r * 32 + ((fch ^ ((r >> 1) & 3)) << 3); }

    auto stA = [&](int tau, int h) {
        int tc = tau < nt ? tau : nt - 1;          // tail clamp: same-value rewrite
        const u16* p = (tc < nts) ? A0 : A1;
        int k = ((tc < nts) ? tc : tc - nts) << 6;
        const u16* src = p + (size_t)(m_base + h * 128) * H_DIM + a_off + k;
        u16* dst = sA + (((tc & 1) * 2 + h) * 2) * 4096 + w * 512;
        gld_lds16(src, dst);                       // slab 0
        gld_lds16(src + 32, dst + 4096);           // slab 1
    };
    auto stB = [&](int tau, int h) {
        int tc = tau < nt ? tau : nt - 1;
        const u16* p = (tc < nts) ? B0 : B1;
        int k = ((tc < nts) ? tc : tc - nts) << 6;
        const u16* src = p + (size_t)(n_base + h * 64) * H_DIM + b_off + k + bj * 32;
        u16* dst = sB + (((tc & 1) * 2 + h) * 2 + bj) * 2048 + (w & 3) * 512;
        gld_lds16(src, dst);
    };

    // prologue: mirror steady state exactly. 10 loads, drain to 4 in flight.
    stA(0, 0); stB(0, 0); stB(0, 1); stA(0, 1);
    stA(1, 0); stB(1, 0); stB(1, 1);
    VMCNT4();               // tile0 fully resident; tile1 h0A/h0B/h1B in flight
    bar_();

    short8 af[4][2], bf0[2], bf1[2];
    const int niter = nt >> 1;
    for (int i = 0; i < niter; ++i) {
        const int t = 2 * i;
        // -------- K-tile t (buf0) --------
        RDA(0, 0); RDB(0, 0, bf0);      // ph1
        stA(t + 1, 1);
        bar_();
        MMAQ(0, 0, bf0);
        bar_();
        RDB(0, 1, bf1);                 // ph2
        stA(t + 2, 0);
        bar_();
        MMAQ(0, 1, bf1);
        bar_();
        RDA(0, 1);                      // ph3
        stB(t + 2, 0);
        bar_();
        MMAQ(1, 0, bf0);
        bar_();
        stB(t + 2, 1);                  // ph4
        bar_();
        MMAQ(1, 1, bf1);
        VMCNT4();                       // tile t+1 now fully resident
        bar_();
        // -------- K-tile t+1 (buf1) --------
        RDA(1, 0); RDB(1, 0, bf0);      // ph5
        stA(t + 2, 1);
        bar_();
        MMAQ(0, 0, bf0);
        bar_();
        RDB(1, 1, bf1);                 // ph6
        stA(t + 3, 0);
        bar_();
        MMAQ(0, 1, bf1);
        bar_();
        RDA(1, 1);                      // ph7
        stB(t + 3, 0);
        bar_();
        MMAQ(1, 0, bf0);
        bar_();
        stB(t + 3, 1);                  // ph8
        bar_();
        MMAQ(1, 1, bf1);
        VMCNT4();                       // tile t+2 now fully resident
        bar_();
    }
}

// ---------------------------------------------------------------------------
// Phase A. grid = (M-tiles=10, N-tiles=25, 3 gates); z slowest so the
// duration-2 blocks (g<2: K=6400 fused) dispatch first (LPT), g=2 singles
// fill the tail -> ~98% CU utilization at 1 block/CU.
// Packed fragment-major output layout (identical formula in phase B):
//   tile(nbi*10+bmi)*32768 + wave*4096 + ((qm*2+qn)*4+mi)*256 + lane*4 + j
// ---------------------------------------------------------------------------
__global__ __launch_bounds__(512, 2) void gru_gemm_a(
    const u16* __restrict__ Xbf, const u16* __restrict__ Hpbf,
    const u16* __restrict__ Wih, const u16* __restrict__ Whh,
    const float* __restrict__ b_ih, const float* __restrict__ b_hh,
    u16* __restrict__ Rb, u16* __restrict__ Zb, u16* __restrict__ Gb) {
    __shared__ u16 sA[32768];   // 64 KB: 2buf x 2half x 2slab x [128][32]
    __shared__ u16 sB[16384];   // 32 KB: 2buf x 2half x 2slab x [64][32]
    floatx4 acc[2][2][4];
    #pragma unroll
    for (int a = 0; a < 2; ++a)
        #pragma unroll
        for (int b = 0; b < 2; ++b)
            #pragma unroll
            for (int c = 0; c < 4; ++c) acc[a][b][c] = (floatx4){0.f, 0.f, 0.f, 0.f};
    const int g = blockIdx.z;
    const int bmi = blockIdx.x, nbi = blockIdx.y;
    const int m_base = bmi * 256, n_base = nbi * 128;
    const size_t gstride = (size_t)H_DIM * H_DIM;
    if (g < 2) {
        kloop8(Xbf, Hpbf, Wih + g * gstride, Whh + g * gstride, 50, 100, m_base, n_base, sA, sB, acc);
    } else {
        kloop8(Hpbf, Hpbf, Whh + 2 * gstride, Whh + 2 * gstride, 50, 50, m_base, n_base, sA, sB, acc);
    }
    u16* outp = (g == 0) ? Rb : (g == 1) ? Zb : Gb;
    const int tid = threadIdx.x;
    const int w = tid >> 6, lane = tid & 63;
    const int wn = w & 3, cc = lane & 15;
    const size_t tbase = (size_t)(nbi * 10 + bmi) * 32768 + w * 4096 + lane * 4;
    #pragma unroll
    for (int qm = 0; qm < 2; ++qm)
        #pragma unroll
        for (int qn = 0; qn < 2; ++qn) {
            int col = n_base + qn * 64 + wn * 16 + cc;
            float bsum;
            if (g == 0)      bsum = b_ih[col] + b_hh[col];
            else if (g == 1) bsum = b_ih[H_DIM + col] + b_hh[H_DIM + col];
            else             bsum = b_hh[2 * H_DIM + col];
            #pragma unroll
            for (int mi = 0; mi < 4; ++mi) {
                short4v o;
                #pragma unroll
                for (int j = 0; j < 4; ++j) {
                    float v = acc[qm][qn][mi][j] + bsum;
                    if (g < 2) v = sigmoidf_(v);
                    o[j] = (short)f2bf(v);
                }
                *(short4v*)(outp + tbase + ((qm * 2 + qn) * 4 + mi) * 256) = o;
            }
        }
}

// ---------------------------------------------------------------------------
// Phase B: gx_n GEMM + GRU combine. Same tile geometry/packing as phase A.
// ---------------------------------------------------------------------------
__global__ __launch_bounds__(512, 2) void gru_gemm_b(
    const u16* __restrict__ Xbf, const u16* __restrict__ Wih,
    const u16* __restrict__ Rb, const u16* __restrict__ Zb, const u16* __restrict__ Gb,
    const float* __restrict__ b_ih,
    const float* __restrict__ hprev, u16* __restrict__ Hn) {
    __shared__ u16 sA[32768];
    __shared__ u16 sB[16384];
    floatx4 acc[2][2][4];
    #pragma unroll
    for (int a = 0; a < 2; ++a)
        #pragma unroll
        for (int b = 0; b < 2; ++b)
            #pragma unroll
            for (int c = 0; c < 4; ++c) acc[a][b][c] = (floatx4){0.f, 0.f, 0.f, 0.f};
    const int bmi = blockIdx.x, nbi = blockIdx.y;
    const int m_base = bmi * 256, n_base = nbi * 128;
    const u16* Wn = Wih + (size_t)2 * H_DIM * H_DIM;
    kloop8(Xbf, Xbf, Wn, Wn, 50, 50, m_base, n_base, sA, sB, acc);
    const int tid = threadIdx.x;
    const int w = tid >> 6, lane = tid & 63;
    const int wm = w >> 2, wn = w & 3;
    const int quad = lane >> 4, cc = lane & 15;
    const size_t tbase = (size_t)(nbi * 10 + bmi) * 32768 + w * 4096 + lane * 4;
    #pragma unroll
    for (int qm = 0; qm < 2; ++qm)
        #pragma unroll
        for (int qn = 0; qn < 2; ++qn) {
            int col = n_base + qn * 64 + wn * 16 + cc;
            float bin_ = b_ih[2 * H_DIM + col];
            #pragma unroll
            for (int mi = 0; mi < 4; ++mi) {
                size_t pidx = tbase + ((qm * 2 + qn) * 4 + mi) * 256;
                short4v rv = *(const short4v*)(Rb + pidx);
                short4v zv = *(const short4v*)(Zb + pidx);
                short4v gv = *(const short4v*)(Gb + pidx);
                int rw = m_base + qm * 128 + wm * 64 + mi * 16 + quad * 4;
                #pragma unroll
                for (int j = 0; j < 4; ++j) {
                    float r = bf2f((u16)rv[j]);
                    float z = bf2f((u16)zv[j]);
                    float gh = bf2f((u16)gv[j]);
                    float n = fast_tanh(acc[qm][qn][mi][j] + bin_ + r * gh);
                    size_t idx = (size_t)(rw + j) * H_DIM + col;
                    float h = hprev[idx];
                    Hn[idx] = f2bf((1.f - z) * n + z * h);
                }
            }
        }
}

#undef RDA
#undef RDB
#undef MMAQ

// ---------------------------------------------------------------------------
// fc1: O = dropout(relu(Hn@fc1_w^T + b)). 128x64 tile bf16 MFMA (unchanged).
// ---------------------------------------------------------------------------
__global__ __launch_bounds__(256) void fc1_k(
    const u16* __restrict__ Hn, const u16* __restrict__ Wb,
    const float* __restrict__ bias, const float* __restrict__ u2,
    const float* __restrict__ pl2, float* __restrict__ O) {
    __shared__ u16 sA[4096], sB[2048];
    floatx4 acc[4][2];
    #pragma unroll
    for (int i = 0; i < 4; ++i) { acc[i][0] = (floatx4){0.f,0.f,0.f,0.f}; acc[i][1] = (floatx4){0.f,0.f,0.f,0.f}; }
    const int tid = threadIdx.x;
    const int wave = tid >> 6, lane = tid & 63;
    const int m_base = blockIdx.y * 128, nb = blockIdx.x * 64;
    const int r = tid >> 2, c = tid & 3;
    const int swe = (c ^ ((r >> 1) & 3)) << 3;
    const u16* Ag = Hn + (size_t)(m_base + r) * H_DIM + swe;
    const u16* Bg = Wb + (size_t)(nb + r) * H_DIM + swe;
    u16* sA0 = sA + wave * 512;
    u16* sB0 = sB + wave * 512;
    const int frow = lane & 15, fch = lane >> 4;
    const int wrow0 = (wave >> 1) * 64, wcol0 = (wave & 1) * 32;
    int aoff[4], boff[2];
    #pragma unroll
    for (int mi = 0; mi < 4; ++mi) {
        int row = wrow0 + mi * 16 + frow;
        aoff[mi] = row * 32 + ((fch ^ ((row >> 1) & 3)) << 3);
    }
    #pragma unroll
    for (int ni = 0; ni < 2; ++ni) {
        int row = wcol0 + ni * 16 + frow;
        boff[ni] = row * 32 + ((fch ^ ((row >> 1) & 3)) << 3);
    }
    for (int kk = 0; kk < 100; ++kk) {
        __syncthreads();
        gld_lds16(Ag + kk * 32, sA0);
        gld_lds16(Ag + kk * 32 + (size_t)64 * H_DIM, sA0 + 2048);
        gld_lds16(Bg + kk * 32, sB0);
        __syncthreads();
        short8 af[4], bfr[2];
        #pragma unroll
        for (int mi = 0; mi < 4; ++mi) af[mi] = *(const short8*)(sA + aoff[mi]);
        #pragma unroll
        for (int ni = 0; ni < 2; ++ni) bfr[ni] = *(const short8*)(sB + boff[ni]);
        #pragma unroll
        for (int mi = 0; mi < 4; ++mi)
            #pragma unroll
            for (int ni = 0; ni < 2; ++ni)
                acc[mi][ni] = __builtin_amdgcn_mfma_f32_16x16x32_bf16(af[mi], bfr[ni], acc[mi][ni], 0, 0, 0);
    }
    float p = sigmoidf_(pl2[0]);
    float lp = __logf(p) - log1pf(-p);
    float inv = 1.0f / (1.0f - p);
    const int quad = lane >> 4, cc = lane & 15;
    #pragma unroll
    for (int ni = 0; ni < 2; ++ni) {
        int col = nb + wcol0 + ni * 16 + cc;
        float bcol = bias[col];
        #pragma unroll
        for (int mi = 0; mi < 4; ++mi) {
            int rw = m_base + wrow0 + mi * 16 + quad * 4;
            #pragma unroll
            for (int j = 0; j < 4; ++j) {
                size_t idx = (size_t)(rw + j) * OUT1 + col;
                float v = fmaxf(acc[mi][ni][j] + bcol, 0.f);
                float u = u2[idx];
                float z = sigmoidf_((lp + __logf(u) - log1pf(-u)) * TEMP_INV);
                O[idx] = v * (1.0f - z) * inv;
            }
        }
    }
}

// ---------------------------------------------------------------------------
// fp32 -> bf16 conversion, 8 elts/thread
// ---------------------------------------------------------------------------
__global__ void cvt_bf16_k(const float* __restrict__ src, u16* __restrict__ dst, int n8) {
    int i = blockIdx.x * 256 + threadIdx.x;
    if (i >= n8) return;
    float4 v0 = *((const float4*)src + 2 * (size_t)i);
    float4 v1 = *((const float4*)src + 2 * (size_t)i + 1);
    short8 o;
    o[0] = (short)f2bf(v0.x); o[1] = (short)f2bf(v0.y);
    o[2] = (short)f2bf(v0.z); o[3] = (short)f2bf(v0.w);
    o[4] = (short)f2bf(v1.x); o[5] = (short)f2bf(v1.y);
    o[6] = (short)f2bf(v1.z); o[7] = (short)f2bf(v1.w);
    *(short8*)(dst + 8 * (size_t)i) = o;
}

// ---------------------------------------------------------------------------
// prep: system model + input concat (fp32, exact)
// ---------------------------------------------------------------------------
__global__ void prep_k(const float* __restrict__ y_t, const float* __restrict__ xfp,
                       const float* __restrict__ xfpp, const float* __restrict__ yprev,
                       const float* __restrict__ dxp, const float* __restrict__ Fm,
                       const float* __restrict__ Hm,
                       float* __restrict__ xpred, float* __restrict__ resid,
                       float* __restrict__ inp) {
    int b = threadIdx.x;
    float xrow[SD], xp[SD];
    for (int k = 0; k < SD; ++k) xrow[k] = xfp[b * SD + k];
    for (int s = 0; s < SD; ++s) {
        float acc = 0.f;
        for (int k = 0; k < SD; ++k) acc += xrow[k] * Fm[s * SD + k];
        xp[s] = tanhf(acc);
        xpred[b * SD + s] = xp[s];
    }
    float res[OD];
    for (int o = 0; o < OD; ++o) {
        float acc = 0.f;
        for (int s = 0; s < SD; ++s) acc += xp[s] * Hm[o * SD + s];
        res[o] = y_t[b * OD + o] - acc;
        resid[b * OD + o] = res[o];
    }
    float* ir = inp + b * IN_DIM;
    for (int k = 0; k < SD; ++k) ir[k] = dxp[b * SD + k];
    for (int o = 0; o < OD; ++o) ir[SD + o] = res[o];
    for (int k = 0; k < SD; ++k) ir[SD + OD + k] = xrow[k] - xfpp[b * SD + k];
    for (int o = 0; o < OD; ++o) ir[SD + OD + SD + o] = yprev[b * OD + o];
}

__global__ void fc_in_k(const float* __restrict__ inp, const float* __restrict__ w,
                        const float* __restrict__ bias, float* __restrict__ a) {
    int b = blockIdx.x;
    __shared__ float row[IN_DIM];
    int t = threadIdx.x;
    if (t < IN_DIM) row[t] = inp[b * IN_DIM + t];
    __syncthreads();
    for (int j = t; j < H_DIM; j += 256) {
        float s = bias[j];
        const float* wr = w + j * IN_DIM;
        #pragma unroll 8
        for (int k = 0; k < IN_DIM; ++k) s += row[k] * wr[k];
        a[b * H_DIM + j] = fmaxf(s, 0.f);
    }
}

// X (bf16) = concrete_dropout(a, u1, p1)
__global__ void dropx_k(const float* __restrict__ a, const float* __restrict__ u1,
                        const float* __restrict__ pl1, u16* __restrict__ X) {
    int idx_in = blockIdx.x * 256 + threadIdx.x;
    int i = blockIdx.y;
    float p = sigmoidf_(pl1[0]);
    float lp = __logf(p) - log1pf(-p);
    float inv = 1.0f / (1.0f - p);
    size_t gidx = (size_t)i * (B_DIM * H_DIM) + idx_in;
    float u = u1[gidx];
    float z = sigmoidf_((lp + __logf(u) - log1pf(-u)) * TEMP_INV);
    X[gidx] = f2bf(a[idx_in] * (1.0f - z) * inv);
}

// K = o @ fc2_w^T + b; xf = x_pred + K @ residual
__global__ void fc2_corr_k(const float* __restrict__ O, const float* __restrict__ w,
                           const float* __restrict__ bias, const float* __restrict__ resid,
                           const float* __restrict__ xpred, float* __restrict__ xf_ens) {
    int row = blockIdx.x;
    int b = row & (B_DIM - 1);
    __shared__ __align__(16) float orow[OUT1];
    int t = threadIdx.x;
    for (int k = t; k < OUT1; k += 128) orow[k] = O[(size_t)row * OUT1 + k];
    __syncthreads();
    int s = t >> 3, oo = t & 7;
    const float* wr = w + (s * OD + oo) * OUT1;
    float sum = 0.f;
    for (int k = 0; k < OUT1; k += 4) {
        float4 ov = *(const float4*)&orow[k];
        float4 wv = *(const float4*)&wr[k];
        sum += ov.x * wv.x + ov.y * wv.y + ov.z * wv.z + ov.w * wv.w;
    }
    sum += bias[s * OD + oo];
    float v = sum * resid[b * OD + oo];
    v += __shfl_down(v, 4, 8);
    v += __shfl_down(v, 2, 8);
    v += __shfl_down(v, 1, 8);
    if (oo == 0) xf_ens[row * SD + s] = xpred[b * SD + s] + v;
}

__global__ void stats_k(const float* __restrict__ xf_ens, float* __restrict__ out) {
    int b = blockIdx.x;
    __shared__ float xf[S_ENS][SD];
    __shared__ float mean[SD];
    int t = threadIdx.x;
    if (t < S_ENS * SD) {
        int s = t >> 4, k = t & 15;
        xf[s][k] = xf_ens[s * (B_DIM * SD) + b * SD + k];
    }
    __syncthreads();
    if (t < SD) {
        float m = 0.f;
        for (int s = 0; s < S_ENS; ++s) m += xf[s][t];
        m *= (1.0f / S_ENS);
        mean[t] = m;
        out[b * SD + t] = m;
    }
    __syncthreads();
    int i = t >> 4, j = t & 15;
    float p = 0.f;
    for (int s = 0; s < S_ENS; ++s) p += (xf[s][i] - mean[i]) * (xf[s][j] - mean[j]);
    out[B_DIM * SD + b * 256 + t] = p * (1.0f / S_ENS);
}

__global__ void sumsq_k(const float* __restrict__ w, int n, float* __restrict__ accum) {
    float s = 0.f;
    for (int i = blockIdx.x * blockDim.x + threadIdx.x; i < n; i += gridDim.x * blockDim.x) {
        float v = w[i];
        s += v * v;
    }
    #pragma unroll
    for (int d = 32; d >= 1; d >>= 1) s += __shfl_down(s, d, 64);
    __shared__ float red[4];
    int lane = threadIdx.x & 63, wv = threadIdx.x >> 6;
    if (lane == 0) red[wv] = s;
    __syncthreads();
    if (threadIdx.x == 0) atomicAdd(accum, red[0] + red[1] + red[2] + red[3]);
}

__global__ void write_reg_k(const float* __restrict__ sums, const float* __restrict__ pl1,
                            const float* __restrict__ pl2, float* __restrict__ out) {
    int t = threadIdx.x;
    float p1 = sigmoidf_(pl1[0]);
    float p2 = sigmoidf_(pl2[0]);
    float ent1 = p1 * logf(p1) + (1.f - p1) * log1pf(-p1);
    float ent2 = p2 * logf(p2) + (1.f - p2) * log1pf(-p2);
    float reg = sums[0] / (1.f - p1) + (float)H_DIM * ent1
              + sums[1] / (1.f - p2) + (float)OUT1 * ent2;
    if (t < S_ENS) out[B_DIM * SD + B_DIM * SD * SD + t] = reg;
}

// ---------------------------------------------------------------------------
extern "C" void kernel_launch(void* const* d_in, const int* in_sizes, int n_in,
                              void* d_out, int out_size, void* d_ws, size_t ws_size,
                              hipStream_t stream) {
    const float* y_t     = (const float*)d_in[0];
    const float* xfp     = (const float*)d_in[1];
    const float* xfpp    = (const float*)d_in[2];
    const float* yprev   = (const float*)d_in[3];
    const float* dxp     = (const float*)d_in[4];
    const float* hprev   = (const float*)d_in[5];
    const float* Fm      = (const float*)d_in[6];
    const float* Hm      = (const float*)d_in[7];
    const float* fc_in_w = (const float*)d_in[8];
    const float* fc_in_b = (const float*)d_in[9];
    const float* W_ih    = (const float*)d_in[10];
    const float* W_hh    = (const float*)d_in[11];
    const float* b_ih    = (const float*)d_in[12];
    const float* b_hh    = (const float*)d_in[13];
    const float* fc1_w   = (const float*)d_in[14];
    const float* fc1_b   = (const float*)d_in[15];
    const float* fc2_w   = (const float*)d_in[16];
    const float* fc2_b   = (const float*)d_in[17];
    const float* pl1     = (const float*)d_in[18];
    const float* pl2     = (const float*)d_in[19];
    const float* u1      = (const float*)d_in[20];
    const float* u2      = (const float*)d_in[21];
    float* out = (float*)d_out;
    char* ws = (char*)d_ws;

    const size_t SZ_W    = (size_t)3 * H_DIM * H_DIM * 2;
    const size_t SZ_MH   = (size_t)M_ROWS * H_DIM * 2;
    size_t off = 0;
    u16* Wihbf  = (u16*)(ws + off); off += SZ_W;
    u16* Whhbf  = (u16*)(ws + off); off += SZ_W;
    u16* Rb     = (u16*)(ws + off); off += SZ_MH;
    u16* Zb     = (u16*)(ws + off); off += SZ_MH;
    u16* Gb     = (u16*)(ws + off); off += SZ_MH;
    u16* Xbf    = (u16*)(ws + off); off += SZ_MH;
    u16* Hpbf   = (u16*)(ws + off); off += SZ_MH;
    u16* Hnbf   = Hpbf;                       // alias: Hpbf dead before phase-B writes
    u16* fc1wbf = (u16*)(ws + off); off += (size_t)OUT1 * H_DIM * 2;
    float* O_buf   = (float*)(ws + off); off += (size_t)M_ROWS * OUT1 * 4;
    float* a_buf   = (float*)(ws + off); off += (size_t)B_DIM * H_DIM * 4;
    float* xf_buf  = (float*)(ws + off); off += (size_t)M_ROWS * SD * 4;
    float* xpred_b = (float*)(ws + off); off += (size_t)B_DIM * SD * 4;
    float* res_b   = (float*)(ws + off); off += (size_t)B_DIM * OD * 4;
    float* inp_b   = (float*)(ws + off); off += (size_t)B_DIM * IN_DIM * 4;
    float* sums_b  = (float*)(ws + off); off += 256;

    hipMemsetAsync(sums_b, 0, 2 * sizeof(float), stream);

    prep_k<<<1, 256, 0, stream>>>(y_t, xfp, xfpp, yprev, dxp, Fm, Hm, xpred_b, res_b, inp_b);
    fc_in_k<<<B_DIM, 256, 0, stream>>>(inp_b, fc_in_w, fc_in_b, a_buf);
    dropx_k<<<dim3(B_DIM * H_DIM / 256, S_ENS), 256, 0, stream>>>(a_buf, u1, pl1, Xbf);

    cvt_bf16_k<<<15000, 256, 0, stream>>>(W_ih, Wihbf, 3 * H_DIM * H_DIM / 8);
    cvt_bf16_k<<<15000, 256, 0, stream>>>(W_hh, Whhbf, 3 * H_DIM * H_DIM / 8);
    cvt_bf16_k<<<4000, 256, 0, stream>>>(hprev, Hpbf, M_ROWS * H_DIM / 8);
    cvt_bf16_k<<<800, 256, 0, stream>>>(fc1_w, fc1wbf, OUT1 * H_DIM / 8);

    // GRU: 256x128 tiles, 8-phase pipelined K-loop. z slowest => the K=6400
    // fused gates (duration-2 blocks) dispatch first (LPT), ghn singles fill tail.
    gru_gemm_a<<<dim3(M_ROWS / 256, H_DIM / 128, 3), 512, 0, stream>>>(
        Xbf, Hpbf, Wihbf, Whhbf, b_ih, b_hh, Rb, Zb, Gb);
    gru_gemm_b<<<dim3(M_ROWS / 256, H_DIM / 128), 512, 0, stream>>>(
        Xbf, Wihbf, Rb, Zb, Gb, b_ih, hprev, Hnbf);

    fc1_k<<<dim3(OUT1 / 64, M_ROWS / 128), 256, 0, stream>>>(Hnbf, fc1wbf, fc1_b, u2, pl2, O_buf);

    fc2_corr_k<<<M_ROWS, 128, 0, stream>>>(O_buf, fc2_w, fc2_b, res_b, xpred_b, xf_buf);
    stats_k<<<B_DIM, 256, 0, stream>>>(xf_buf, out);
    sumsq_k<<<256, 256, 0, stream>>>(fc_in_w, H_DIM * IN_DIM, sums_b);
    sumsq_k<<<1024, 256, 0, stream>>>(fc1_w, OUT1 * H_DIM, sums_b + 1);
    write_reg_k<<<1, 64, 0, stream>>>(sums_b, pl1, pl2, out);
}

// Round 4
// 989.468 us; speedup vs baseline: 1.0972x; 1.0972x over previous
//
#include <hip/hip_runtime.h>
#include <hip/hip_bf16.h>
#include <math.h>

// Problem constants
#define S_ENS 10
#define B_DIM 256
#define SD 16
#define OD 8
#define H_DIM 3200
#define OUT1 512
#define IN_DIM 48
#define M_ROWS (S_ENS * B_DIM)     // 2560
#define TEMP_INV 10.0f

typedef unsigned short u16;
typedef __attribute__((ext_vector_type(8))) short short8;
typedef __attribute__((ext_vector_type(4))) short short4v;   // 8B packed bf16x4
typedef __attribute__((ext_vector_type(4))) float floatx4;

__device__ __forceinline__ float sigmoidf_(float x) { return 1.0f / (1.0f + __expf(-x)); }
__device__ __forceinline__ float fast_tanh(float x) {
    x = fminf(fmaxf(x, -15.f), 15.f);
    float e = __expf(2.f * x);
    return (e - 1.f) / (e + 1.f);
}

// fp32 -> bf16 round-to-nearest-even
__device__ __forceinline__ u16 f2bf(float f) {
    union { float f; unsigned u; } v; v.f = f;
    unsigned u = v.u + 0x7fffu + ((v.u >> 16) & 1u);
    return (u16)(u >> 16);
}
__device__ __forceinline__ float bf2f(u16 h) {
    union { unsigned u; float f; } v; v.u = ((unsigned)h) << 16;
    return v.f;
}

// async global->LDS, 16B per lane. LDS dest: wave-uniform base + lane*16.
__device__ __forceinline__ void gld_lds16(const u16* g, u16* l) {
    __builtin_amdgcn_global_load_lds((const __attribute__((address_space(1))) void*)g,
                                     (__attribute__((address_space(3))) void*)l, 16, 0, 0);
}

// Raw barrier with compiler-level memory fence + sched pin (NO auto vmcnt(0)).
__device__ __forceinline__ void bar_() {
    __builtin_amdgcn_sched_barrier(0);
    asm volatile("" ::: "memory");
    __builtin_amdgcn_s_barrier();
    asm volatile("" ::: "memory");
    __builtin_amdgcn_sched_barrier(0);
}
#define VMCNT4() asm volatile("s_waitcnt vmcnt(4)" ::: "memory")

// ---------------------------------------------------------------------------
// 128x128-tile bf16 MFMA K-loop, BK=64 (2x K=32 slabs), double-buffered,
// 2-phase counted-vmcnt pipeline, 4 waves (256 thr), 64 KB LDS -> 2 blocks/CU.
// Chunk-XOR swizzled LDS (round-0-verified: SQ_LDS_BANK_CONFLICT == 0).
//
// Per K-tile t (buf = t&1), 16 MFMA per barrier-pair (template ratio):
//  ph1: ds_read A(t) all 4mi x 2slab + B(t) ni=0,1;  stage B(t+1) [4 gld]
//       bar; setprio1; 16 MFMA (mi x ni01 x slab); setprio0; bar
//  ph2: ds_read B(t) ni=2,3;                         stage A(t+2) [4 gld]
//       bar; setprio1; 16 MFMA (mi x ni23 x slab); setprio0; VMCNT(4); bar
// vmcnt(4) guards tile t+1 residency (4 = loads issued after B(t+1)).
// Slot liveness: B(t+1) overwrites B(t-1) (dead end ph2(t-1), consumed in regs
// before that barrier); A(t+2) overwrites A(t) (dead end ph1(t)). Tail clamp
// re-writes identical bytes over the live resident tile (benign; validated r2).
//
// K axis concatenates two operand pairs: tiles [0,nts) -> (A0,B0), tiles
// [nts,nt) -> (A1,B1) (fuses X@Wih + Hp@Whh, K=6400, single prologue).
// ---------------------------------------------------------------------------
__device__ __forceinline__ void kloop128(
    const u16* __restrict__ A0, const u16* __restrict__ A1,
    const u16* __restrict__ B0, const u16* __restrict__ B1,
    int nts, int nt, int m_base, int n_base,
    u16* sA, u16* sB, floatx4 (&acc)[4][4])
{
    const int tid = threadIdx.x;
    const int wave = tid >> 6, lane = tid & 63;
    // staging lane geometry (pre-swizzled global source, linear LDS dest)
    const int r = tid >> 2, c = tid & 3;
    const int swe = (c ^ ((r >> 1) & 3)) << 3;
    // fragment ds_read offsets (elems), same verified swizzle
    const int frow = lane & 15, fch = lane >> 4;
    const int wrow0 = (wave >> 1) * 64, wcol0 = (wave & 1) * 64;
    int aoff[4], boff[4];
    #pragma unroll
    for (int mi = 0; mi < 4; ++mi) {
        int row = wrow0 + mi * 16 + frow;
        aoff[mi] = row * 32 + ((fch ^ ((row >> 1) & 3)) << 3);
    }
    #pragma unroll
    for (int ni = 0; ni < 4; ++ni) {
        int row = wcol0 + ni * 16 + frow;
        boff[ni] = row * 32 + ((fch ^ ((row >> 1) & 3)) << 3);
    }

    // stage one full K-tile (2 slabs x 2 row-halves = 4 gld_lds16)
    auto stA = [&](int tau) {
        int tc = tau < nt ? tau : nt - 1;          // tail clamp (same-value rewrite)
        const u16* p = (tc < nts) ? A0 : A1;
        int k = ((tc < nts) ? tc : tc - nts) << 6;
        const u16* src = p + (size_t)(m_base + r) * H_DIM + swe + k;
        u16* dst = sA + (tc & 1) * 8192 + wave * 512;
        gld_lds16(src, dst);                               // slab0 rows 0-63
        gld_lds16(src + (size_t)64 * H_DIM, dst + 2048);   // slab0 rows 64-127
        gld_lds16(src + 32, dst + 4096);                   // slab1 rows 0-63
        gld_lds16(src + 32 + (size_t)64 * H_DIM, dst + 6144);
    };
    auto stB = [&](int tau) {
        int tc = tau < nt ? tau : nt - 1;
        const u16* p = (tc < nts) ? B0 : B1;
        int k = ((tc < nts) ? tc : tc - nts) << 6;
        const u16* src = p + (size_t)(n_base + r) * H_DIM + swe + k;
        u16* dst = sB + (tc & 1) * 8192 + wave * 512;
        gld_lds16(src, dst);
        gld_lds16(src + (size_t)64 * H_DIM, dst + 2048);
        gld_lds16(src + 32, dst + 4096);
        gld_lds16(src + 32 + (size_t)64 * H_DIM, dst + 6144);
    };

    // prologue: A(0),B(0),A(1) = 12 loads; drain to 4 in flight (A1 may pend).
    stA(0); stB(0); stA(1);
    VMCNT4();
    bar_();

    for (int t = 0; t < nt; ++t) {
        const int bo = (t & 1) * 8192;
        short8 af[4][2], bfr[4][2];
        // ---- ph1: A full + B lo, stage B(t+1) ----
        #pragma unroll
        for (int mi = 0; mi < 4; ++mi) {
            af[mi][0] = *(const short8*)(sA + bo + aoff[mi]);
            af[mi][1] = *(const short8*)(sA + bo + 4096 + aoff[mi]);
        }
        #pragma unroll
        for (int ni = 0; ni < 2; ++ni) {
            bfr[ni][0] = *(const short8*)(sB + bo + boff[ni]);
            bfr[ni][1] = *(const short8*)(sB + bo + 4096 + boff[ni]);
        }
        stB(t + 1);
        bar_();
        __builtin_amdgcn_s_setprio(1);
        #pragma unroll
        for (int mi = 0; mi < 4; ++mi)
            #pragma unroll
            for (int ni = 0; ni < 2; ++ni) {
                acc[mi][ni] = __builtin_amdgcn_mfma_f32_16x16x32_bf16(af[mi][0], bfr[ni][0], acc[mi][ni], 0, 0, 0);
                acc[mi][ni] = __builtin_amdgcn_mfma_f32_16x16x32_bf16(af[mi][1], bfr[ni][1], acc[mi][ni], 0, 0, 0);
            }
        __builtin_amdgcn_s_setprio(0);
        bar_();
        // ---- ph2: B hi, stage A(t+2) ----
        #pragma unroll
        for (int ni = 2; ni < 4; ++ni) {
            bfr[ni][0] = *(const short8*)(sB + bo + boff[ni]);
            bfr[ni][1] = *(const short8*)(sB + bo + 4096 + boff[ni]);
        }
        stA(t + 2);
        bar_();
        __builtin_amdgcn_s_setprio(1);
        #pragma unroll
        for (int mi = 0; mi < 4; ++mi)
            #pragma unroll
            for (int ni = 2; ni < 4; ++ni) {
                acc[mi][ni] = __builtin_amdgcn_mfma_f32_16x16x32_bf16(af[mi][0], bfr[ni][0], acc[mi][ni], 0, 0, 0);
                acc[mi][ni] = __builtin_amdgcn_mfma_f32_16x16x32_bf16(af[mi][1], bfr[ni][1], acc[mi][ni], 0, 0, 0);
            }
        __builtin_amdgcn_s_setprio(0);
        VMCNT4();                      // tile t+1 fully resident after this
        bar_();
    }
}

// ---------------------------------------------------------------------------
// Phase A. grid = (M-tiles=20, N-tiles=25, 3); x fastest => concurrent blocks
// share the same W-tile (L2/L3 reuse). z slowest: fused K=6400 gates first.
// Output PACKED fragment-major (round-0 layout):
//   tile(nbi*20+bmi)*16384 + wave*4096 + (mi*4+ni)*256 + lane*4 + j
// ---------------------------------------------------------------------------
__global__ __launch_bounds__(256) void gru_gemm_a(
    const u16* __restrict__ Xbf, const u16* __restrict__ Hpbf,
    const u16* __restrict__ Wih, const u16* __restrict__ Whh,
    const float* __restrict__ b_ih, const float* __restrict__ b_hh,
    u16* __restrict__ Rb, u16* __restrict__ Zb, u16* __restrict__ Gb) {
    __shared__ u16 sA[16384], sB[16384];   // 64 KB total -> 2 blocks/CU
    floatx4 acc[4][4];
    #pragma unroll
    for (int i = 0; i < 4; ++i)
        #pragma unroll
        for (int j = 0; j < 4; ++j) acc[i][j] = (floatx4){0.f, 0.f, 0.f, 0.f};
    const int g = blockIdx.z;
    const int bmi = blockIdx.x, nbi = blockIdx.y;
    const int m_base = bmi * 128, nb = nbi * 128;
    const size_t gstride = (size_t)H_DIM * H_DIM;
    if (g < 2) {
        kloop128(Xbf, Hpbf, Wih + g * gstride, Whh + g * gstride, 50, 100, m_base, nb, sA, sB, acc);
    } else {
        kloop128(Hpbf, Hpbf, Whh + 2 * gstride, Whh + 2 * gstride, 50, 50, m_base, nb, sA, sB, acc);
    }
    u16* outp = (g == 0) ? Rb : (g == 1) ? Zb : Gb;
    const int lane = threadIdx.x & 63, wave = threadIdx.x >> 6;
    const int wcol0 = (wave & 1) * 64, cc = lane & 15;
    const size_t tbase = (size_t)(nbi * 20 + bmi) * 16384 + wave * 4096 + lane * 4;
    #pragma unroll
    for (int ni = 0; ni < 4; ++ni) {
        int col = nb + wcol0 + ni * 16 + cc;
        float bsum;
        if (g == 0)      bsum = b_ih[col] + b_hh[col];
        else if (g == 1) bsum = b_ih[H_DIM + col] + b_hh[H_DIM + col];
        else             bsum = b_hh[2 * H_DIM + col];
        #pragma unroll
        for (int mi = 0; mi < 4; ++mi) {
            short4v o;
            #pragma unroll
            for (int j = 0; j < 4; ++j) {
                float v = acc[mi][ni][j] + bsum;
                if (g < 2) v = sigmoidf_(v);
                o[j] = (short)f2bf(v);
            }
            *(short4v*)(outp + tbase + (mi * 4 + ni) * 256) = o;
        }
    }
}

// ---------------------------------------------------------------------------
// Phase B: gx_n GEMM + GRU combine. Reads packed r/z/ghn' (8B coalesced),
// fast tanh, writes Hn row-major bf16.
// ---------------------------------------------------------------------------
__global__ __launch_bounds__(256) void gru_gemm_b(
    const u16* __restrict__ Xbf, const u16* __restrict__ Wih,
    const u16* __restrict__ Rb, const u16* __restrict__ Zb, const u16* __restrict__ Gb,
    const float* __restrict__ b_ih,
    const float* __restrict__ hprev, u16* __restrict__ Hn) {
    __shared__ u16 sA[16384], sB[16384];
    floatx4 acc[4][4];
    #pragma unroll
    for (int i = 0; i < 4; ++i)
        #pragma unroll
        for (int j = 0; j < 4; ++j) acc[i][j] = (floatx4){0.f, 0.f, 0.f, 0.f};
    const int bmi = blockIdx.x, nbi = blockIdx.y;
    const int m_base = bmi * 128, nb = nbi * 128;
    const u16* Wn = Wih + (size_t)2 * H_DIM * H_DIM;
    kloop128(Xbf, Xbf, Wn, Wn, 50, 50, m_base, nb, sA, sB, acc);
    const int lane = threadIdx.x & 63, wave = threadIdx.x >> 6;
    const int wrow0 = (wave >> 1) * 64, wcol0 = (wave & 1) * 64;
    const int quad = lane >> 4, cc = lane & 15;
    const size_t tbase = (size_t)(nbi * 20 + bmi) * 16384 + wave * 4096 + lane * 4;
    #pragma unroll
    for (int ni = 0; ni < 4; ++ni) {
        int col = nb + wcol0 + ni * 16 + cc;
        float bin_ = b_ih[2 * H_DIM + col];
        #pragma unroll
        for (int mi = 0; mi < 4; ++mi) {
            size_t pidx = tbase + (mi * 4 + ni) * 256;
            short4v rv = *(const short4v*)(Rb + pidx);
            short4v zv = *(const short4v*)(Zb + pidx);
            short4v gv = *(const short4v*)(Gb + pidx);
            int rw = m_base + wrow0 + mi * 16 + quad * 4;
            #pragma unroll
            for (int j = 0; j < 4; ++j) {
                float r = bf2f((u16)rv[j]);
                float z = bf2f((u16)zv[j]);
                float gh = bf2f((u16)gv[j]);
                float n = fast_tanh(acc[mi][ni][j] + bin_ + r * gh);
                size_t idx = (size_t)(rw + j) * H_DIM + col;
                float h = hprev[idx];
                Hn[idx] = f2bf((1.f - z) * n + z * h);
            }
        }
    }
}

// ---------------------------------------------------------------------------
// fc1: O = dropout(relu(Hn@fc1_w^T + b)). 128x64 tile bf16 MFMA (round-0).
// ---------------------------------------------------------------------------
__global__ __launch_bounds__(256) void fc1_k(
    const u16* __restrict__ Hn, const u16* __restrict__ Wb,
    const float* __restrict__ bias, const float* __restrict__ u2,
    const float* __restrict__ pl2, float* __restrict__ O) {
    __shared__ u16 sA[4096], sB[2048];
    floatx4 acc[4][2];
    #pragma unroll
    for (int i = 0; i < 4; ++i) { acc[i][0] = (floatx4){0.f,0.f,0.f,0.f}; acc[i][1] = (floatx4){0.f,0.f,0.f,0.f}; }
    const int tid = threadIdx.x;
    const int wave = tid >> 6, lane = tid & 63;
    const int m_base = blockIdx.y * 128, nb = blockIdx.x * 64;
    const int r = tid >> 2, c = tid & 3;
    const int swe = (c ^ ((r >> 1) & 3)) << 3;
    const u16* Ag = Hn + (size_t)(m_base + r) * H_DIM + swe;
    const u16* Bg = Wb + (size_t)(nb + r) * H_DIM + swe;
    u16* sA0 = sA + wave * 512;
    u16* sB0 = sB + wave * 512;
    const int frow = lane & 15, fch = lane >> 4;
    const int wrow0 = (wave >> 1) * 64, wcol0 = (wave & 1) * 32;
    int aoff[4], boff[2];
    #pragma unroll
    for (int mi = 0; mi < 4; ++mi) {
        int row = wrow0 + mi * 16 + frow;
        aoff[mi] = row * 32 + ((fch ^ ((row >> 1) & 3)) << 3);
    }
    #pragma unroll
    for (int ni = 0; ni < 2; ++ni) {
        int row = wcol0 + ni * 16 + frow;
        boff[ni] = row * 32 + ((fch ^ ((row >> 1) & 3)) << 3);
    }
    for (int kk = 0; kk < 100; ++kk) {
        __syncthreads();
        gld_lds16(Ag + kk * 32, sA0);
        gld_lds16(Ag + kk * 32 + (size_t)64 * H_DIM, sA0 + 2048);
        gld_lds16(Bg + kk * 32, sB0);
        __syncthreads();
        short8 af[4], bfr[2];
        #pragma unroll
        for (int mi = 0; mi < 4; ++mi) af[mi] = *(const short8*)(sA + aoff[mi]);
        #pragma unroll
        for (int ni = 0; ni < 2; ++ni) bfr[ni] = *(const short8*)(sB + boff[ni]);
        #pragma unroll
        for (int mi = 0; mi < 4; ++mi)
            #pragma unroll
            for (int ni = 0; ni < 2; ++ni)
                acc[mi][ni] = __builtin_amdgcn_mfma_f32_16x16x32_bf16(af[mi], bfr[ni], acc[mi][ni], 0, 0, 0);
    }
    float p = sigmoidf_(pl2[0]);
    float lp = __logf(p) - log1pf(-p);
    float inv = 1.0f / (1.0f - p);
    const int quad = lane >> 4, cc = lane & 15;
    #pragma unroll
    for (int ni = 0; ni < 2; ++ni) {
        int col = nb + wcol0 + ni * 16 + cc;
        float bcol = bias[col];
        #pragma unroll
        for (int mi = 0; mi < 4; ++mi) {
            int rw = m_base + wrow0 + mi * 16 + quad * 4;
            #pragma unroll
            for (int j = 0; j < 4; ++j) {
                size_t idx = (size_t)(rw + j) * OUT1 + col;
                float v = fmaxf(acc[mi][ni][j] + bcol, 0.f);
                float u = u2[idx];
                float z = sigmoidf_((lp + __logf(u) - log1pf(-u)) * TEMP_INV);
                O[idx] = v * (1.0f - z) * inv;
            }
        }
    }
}

// ---------------------------------------------------------------------------
// fp32 -> bf16 conversion, 8 elts/thread
// ---------------------------------------------------------------------------
__global__ void cvt_bf16_k(const float* __restrict__ src, u16* __restrict__ dst, int n8) {
    int i = blockIdx.x * 256 + threadIdx.x;
    if (i >= n8) return;
    float4 v0 = *((const float4*)src + 2 * (size_t)i);
    float4 v1 = *((const float4*)src + 2 * (size_t)i + 1);
    short8 o;
    o[0] = (short)f2bf(v0.x); o[1] = (short)f2bf(v0.y);
    o[2] = (short)f2bf(v0.z); o[3] = (short)f2bf(v0.w);
    o[4] = (short)f2bf(v1.x); o[5] = (short)f2bf(v1.y);
    o[6] = (short)f2bf(v1.z); o[7] = (short)f2bf(v1.w);
    *(short8*)(dst + 8 * (size_t)i) = o;
}

// ---------------------------------------------------------------------------
// prep: system model + input concat (fp32, exact)
// ---------------------------------------------------------------------------
__global__ void prep_k(const float* __restrict__ y_t, const float* __restrict__ xfp,
                       const float* __restrict__ xfpp, const float* __restrict__ yprev,
                       const float* __restrict__ dxp, const float* __restrict__ Fm,
                       const float* __restrict__ Hm,
                       float* __restrict__ xpred, float* __restrict__ resid,
                       float* __restrict__ inp) {
    int b = threadIdx.x;
    float xrow[SD], xp[SD];
    for (int k = 0; k < SD; ++k) xrow[k] = xfp[b * SD + k];
    for (int s = 0; s < SD; ++s) {
        float acc = 0.f;
        for (int k = 0; k < SD; ++k) acc += xrow[k] * Fm[s * SD + k];
        xp[s] = tanhf(acc);
        xpred[b * SD + s] = xp[s];
    }
    float res[OD];
    for (int o = 0; o < OD; ++o) {
        float acc = 0.f;
        for (int s = 0; s < SD; ++s) acc += xp[s] * Hm[o * SD + s];
        res[o] = y_t[b * OD + o] - acc;
        resid[b * OD + o] = res[o];
    }
    float* ir = inp + b * IN_DIM;
    for (int k = 0; k < SD; ++k) ir[k] = dxp[b * SD + k];
    for (int o = 0; o < OD; ++o) ir[SD + o] = res[o];
    for (int k = 0; k < SD; ++k) ir[SD + OD + k] = xrow[k] - xfpp[b * SD + k];
    for (int o = 0; o < OD; ++o) ir[SD + OD + SD + o] = yprev[b * OD + o];
}

__global__ void fc_in_k(const float* __restrict__ inp, const float* __restrict__ w,
                        const float* __restrict__ bias, float* __restrict__ a) {
    int b = blockIdx.x;
    __shared__ float row[IN_DIM];
    int t = threadIdx.x;
    if (t < IN_DIM) row[t] = inp[b * IN_DIM + t];
    __syncthreads();
    for (int j = t; j < H_DIM; j += 256) {
        float s = bias[j];
        const float* wr = w + j * IN_DIM;
        #pragma unroll 8
        for (int k = 0; k < IN_DIM; ++k) s += row[k] * wr[k];
        a[b * H_DIM + j] = fmaxf(s, 0.f);
    }
}

// X (bf16) = concrete_dropout(a, u1, p1)
__global__ void dropx_k(const float* __restrict__ a, const float* __restrict__ u1,
                        const float* __restrict__ pl1, u16* __restrict__ X) {
    int idx_in = blockIdx.x * 256 + threadIdx.x;
    int i = blockIdx.y;
    float p = sigmoidf_(pl1[0]);
    float lp = __logf(p) - log1pf(-p);
    float inv = 1.0f / (1.0f - p);
    size_t gidx = (size_t)i * (B_DIM * H_DIM) + idx_in;
    float u = u1[gidx];
    float z = sigmoidf_((lp + __logf(u) - log1pf(-u)) * TEMP_INV);
    X[gidx] = f2bf(a[idx_in] * (1.0f - z) * inv);
}

// K = o @ fc2_w^T + b; xf = x_pred + K @ residual
__global__ void fc2_corr_k(const float* __restrict__ O, const float* __restrict__ w,
                           const float* __restrict__ bias, const float* __restrict__ resid,
                           const float* __restrict__ xpred, float* __restrict__ xf_ens) {
    int row = blockIdx.x;
    int b = row & (B_DIM - 1);
    __shared__ __align__(16) float orow[OUT1];
    int t = threadIdx.x;
    for (int k = t; k < OUT1; k += 128) orow[k] = O[(size_t)row * OUT1 + k];
    __syncthreads();
    int s = t >> 3, oo = t & 7;
    const float* wr = w + (s * OD + oo) * OUT1;
    float sum = 0.f;
    for (int k = 0; k < OUT1; k += 4) {
        float4 ov = *(const float4*)&orow[k];
        float4 wv = *(const float4*)&wr[k];
        sum += ov.x * wv.x + ov.y * wv.y + ov.z * wv.z + ov.w * wv.w;
    }
    sum += bias[s * OD + oo];
    float v = sum * resid[b * OD + oo];
    v += __shfl_down(v, 4, 8);
    v += __shfl_down(v, 2, 8);
    v += __shfl_down(v, 1, 8);
    if (oo == 0) xf_ens[row * SD + s] = xpred[b * SD + s] + v;
}

__global__ void stats_k(const float* __restrict__ xf_ens, float* __restrict__ out) {
    int b = blockIdx.x;
    __shared__ float xf[S_ENS][SD];
    __shared__ float mean[SD];
    int t = threadIdx.x;
    if (t < S_ENS * SD) {
        int s = t >> 4, k = t & 15;
        xf[s][k] = xf_ens[s * (B_DIM * SD) + b * SD + k];
    }
    __syncthreads();
    if (t < SD) {
        float m = 0.f;
        for (int s = 0; s < S_ENS; ++s) m += xf[s][t];
        m *= (1.0f / S_ENS);
        mean[t] = m;
        out[b * SD + t] = m;
    }
    __syncthreads();
    int i = t >> 4, j = t & 15;
    float p = 0.f;
    for (int s = 0; s < S_ENS; ++s) p += (xf[s][i] - mean[i]) * (xf[s][j] - mean[j]);
    out[B_DIM * SD + b * 256 + t] = p * (1.0f / S_ENS);
}

__global__ void sumsq_k(const float* __restrict__ w, int n, float* __restrict__ accum) {
    float s = 0.f;
    for (int i = blockIdx.x * blockDim.x + threadIdx.x; i < n; i += gridDim.x * blockDim.x) {
        float v = w[i];
        s += v * v;
    }
    #pragma unroll
    for (int d = 32; d >= 1; d >>= 1) s += __shfl_down(s, d, 64);
    __shared__ float red[4];
    int lane = threadIdx.x & 63, wv = threadIdx.x >> 6;
    if (lane == 0) red[wv] = s;
    __syncthreads();
    if (threadIdx.x == 0) atomicAdd(accum, red[0] + red[1] + red[2] + red[3]);
}

__global__ void write_reg_k(const float* __restrict__ sums, const float* __restrict__ pl1,
                            const float* __restrict__ pl2, float* __restrict__ out) {
    int t = threadIdx.x;
    float p1 = sigmoidf_(pl1[0]);
    float p2 = sigmoidf_(pl2[0]);
    float ent1 = p1 * logf(p1) + (1.f - p1) * log1pf(-p1);
    float ent2 = p2 * logf(p2) + (1.f - p2) * log1pf(-p2);
    float reg = sums[0] / (1.f - p1) + (float)H_DIM * ent1
              + sums[1] / (1.f - p2) + (float)OUT1 * ent2;
    if (t < S_ENS) out[B_DIM * SD + B_DIM * SD * SD + t] = reg;
}

// ---------------------------------------------------------------------------
extern "C" void kernel_launch(void* const* d_in, const int* in_sizes, int n_in,
                              void* d_out, int out_size, void* d_ws, size_t ws_size,
                              hipStream_t stream) {
    const float* y_t     = (const float*)d_in[0];
    const float* xfp     = (const float*)d_in[1];
    const float* xfpp    = (const float*)d_in[2];
    const float* yprev   = (const float*)d_in[3];
    const float* dxp     = (const float*)d_in[4];
    const float* hprev   = (const float*)d_in[5];
    const float* Fm      = (const float*)d_in[6];
    const float* Hm      = (const float*)d_in[7];
    const float* fc_in_w = (const float*)d_in[8];
    const float* fc_in_b = (const float*)d_in[9];
    const float* W_ih    = (const float*)d_in[10];
    const float* W_hh    = (const float*)d_in[11];
    const float* b_ih    = (const float*)d_in[12];
    const float* b_hh    = (const float*)d_in[13];
    const float* fc1_w   = (const float*)d_in[14];
    const float* fc1_b   = (const float*)d_in[15];
    const float* fc2_w   = (const float*)d_in[16];
    const float* fc2_b   = (const float*)d_in[17];
    const float* pl1     = (const float*)d_in[18];
    const float* pl2     = (const float*)d_in[19];
    const float* u1      = (const float*)d_in[20];
    const float* u2      = (const float*)d_in[21];
    float* out = (float*)d_out;
    char* ws = (char*)d_ws;

    const size_t SZ_W    = (size_t)3 * H_DIM * H_DIM * 2;
    const size_t SZ_MH   = (size_t)M_ROWS * H_DIM * 2;
    size_t off = 0;
    u16* Wihbf  = (u16*)(ws + off); off += SZ_W;
    u16* Whhbf  = (u16*)(ws + off); off += SZ_W;
    u16* Rb     = (u16*)(ws + off); off += SZ_MH;
    u16* Zb     = (u16*)(ws + off); off += SZ_MH;
    u16* Gb     = (u16*)(ws + off); off += SZ_MH;
    u16* Xbf    = (u16*)(ws + off); off += SZ_MH;
    u16* Hpbf   = (u16*)(ws + off); off += SZ_MH;
    u16* Hnbf   = Hpbf;                       // alias: Hpbf dead before phase-B writes
    u16* fc1wbf = (u16*)(ws + off); off += (size_t)OUT1 * H_DIM * 2;
    float* O_buf   = (float*)(ws + off); off += (size_t)M_ROWS * OUT1 * 4;
    float* a_buf   = (float*)(ws + off); off += (size_t)B_DIM * H_DIM * 4;
    float* xf_buf  = (float*)(ws + off); off += (size_t)M_ROWS * SD * 4;
    float* xpred_b = (float*)(ws + off); off += (size_t)B_DIM * SD * 4;
    float* res_b   = (float*)(ws + off); off += (size_t)B_DIM * OD * 4;
    float* inp_b   = (float*)(ws + off); off += (size_t)B_DIM * IN_DIM * 4;
    float* sums_b  = (float*)(ws + off); off += 256;

    hipMemsetAsync(sums_b, 0, 2 * sizeof(float), stream);

    prep_k<<<1, 256, 0, stream>>>(y_t, xfp, xfpp, yprev, dxp, Fm, Hm, xpred_b, res_b, inp_b);
    fc_in_k<<<B_DIM, 256, 0, stream>>>(inp_b, fc_in_w, fc_in_b, a_buf);
    dropx_k<<<dim3(B_DIM * H_DIM / 256, S_ENS), 256, 0, stream>>>(a_buf, u1, pl1, Xbf);

    cvt_bf16_k<<<15000, 256, 0, stream>>>(W_ih, Wihbf, 3 * H_DIM * H_DIM / 8);
    cvt_bf16_k<<<15000, 256, 0, stream>>>(W_hh, Whhbf, 3 * H_DIM * H_DIM / 8);
    cvt_bf16_k<<<4000, 256, 0, stream>>>(hprev, Hpbf, M_ROWS * H_DIM / 8);
    cvt_bf16_k<<<800, 256, 0, stream>>>(fc1_w, fc1wbf, OUT1 * H_DIM / 8);

    // GRU: 128x128 tiles, BK=64 dbuf 2-phase pipelined K-loop, 2 blocks/CU.
    gru_gemm_a<<<dim3(M_ROWS / 128, H_DIM / 128, 3), 256, 0, stream>>>(
        Xbf, Hpbf, Wihbf, Whhbf, b_ih, b_hh, Rb, Zb, Gb);
    gru_gemm_b<<<dim3(M_ROWS / 128, H_DIM / 128), 256, 0, stream>>>(
        Xbf, Wihbf, Rb, Zb, Gb, b_ih, hprev, Hnbf);

    fc1_k<<<dim3(OUT1 / 64, M_ROWS / 128), 256, 0, stream>>>(Hnbf, fc1wbf, fc1_b, u2, pl2, O_buf);

    fc2_corr_k<<<M_ROWS, 128, 0, stream>>>(O_buf, fc2_w, fc2_b, res_b, xpred_b, xf_buf);
    stats_k<<<B_DIM, 256, 0, stream>>>(xf_buf, out);
    sumsq_k<<<256, 256, 0, stream>>>(fc_in_w, H_DIM * IN_DIM, sums_b);
    sumsq_k<<<1024, 256, 0, stream>>>(fc1_w, OUT1 * H_DIM, sums_b + 1);
    write_reg_k<<<1, 64, 0, stream>>>(sums_b, pl1, pl2, out);
}

// Round 5
// 963.479 us; speedup vs baseline: 1.1268x; 1.0270x over previous
//
#include <hip/hip_runtime.h>
#include <hip/hip_bf16.h>
#include <math.h>

// Problem constants
#define S_ENS 10
#define B_DIM 256
#define SD 16
#define OD 8
#define H_DIM 3200
#define OUT1 512
#define IN_DIM 48
#define M_ROWS (S_ENS * B_DIM)     // 2560
#define TEMP_INV 10.0f

typedef unsigned short u16;
typedef __attribute__((ext_vector_type(8))) short short8;
typedef __attribute__((ext_vector_type(4))) short short4v;   // 8B packed bf16x4
typedef __attribute__((ext_vector_type(4))) float floatx4;

__device__ __forceinline__ float sigmoidf_(float x) { return 1.0f / (1.0f + __expf(-x)); }
__device__ __forceinline__ float fast_tanh(float x) {
    x = fminf(fmaxf(x, -15.f), 15.f);
    float e = __expf(2.f * x);
    return (e - 1.f) / (e + 1.f);
}

// fp32 -> bf16 round-to-nearest-even
__device__ __forceinline__ u16 f2bf(float f) {
    union { float f; unsigned u; } v; v.f = f;
    unsigned u = v.u + 0x7fffu + ((v.u >> 16) & 1u);
    return (u16)(u >> 16);
}
__device__ __forceinline__ float bf2f(u16 h) {
    union { unsigned u; float f; } v; v.u = ((unsigned)h) << 16;
    return v.f;
}

// async global->LDS, 16B per lane. LDS dest: wave-uniform base + lane*16.
__device__ __forceinline__ void gld_lds16(const u16* g, u16* l) {
    __builtin_amdgcn_global_load_lds((const __attribute__((address_space(1))) void*)g,
                                     (__attribute__((address_space(3))) void*)l, 16, 0, 0);
}

// Raw barrier with compiler-level memory fence + sched pin (NO auto vmcnt(0)).
__device__ __forceinline__ void bar_() {
    __builtin_amdgcn_sched_barrier(0);
    asm volatile("" ::: "memory");
    __builtin_amdgcn_s_barrier();
    asm volatile("" ::: "memory");
    __builtin_amdgcn_sched_barrier(0);
}
#define VMCNT8() asm volatile("s_waitcnt vmcnt(8)" ::: "memory")

// ---------------------------------------------------------------------------
// 128x128-tile bf16 MFMA K-loop, BK=64 (2x K=32 slabs), double-buffered,
// 4 waves (256 thr), 64 KB LDS -> 2 blocks/CU.
// Chunk-XOR swizzled LDS (verified: SQ_LDS_BANK_CONFLICT == 0).
//
// v2 schedule (r4 post-mortem: B was only 1 phase deep -> vmcnt stall):
//  ph1(t): ds_read ALL 16 frags of tile t (A 4mi x 2slab, B 4ni x 2slab;
//          ni=2,3 read LAST so MFMA1 waits only on the first 12 via
//          compiler partial lgkmcnt; ni23 latency hides under MFMA1)
//          bar(B1); setprio1; 16 MFMA (ni 0,1); setprio0; bar(B2)
//  ph2(t): stage A(t+2)+B(t+2) [8 gld, clustered];
//          setprio1; 16 MFMA (ni 2,3); setprio0; VMCNT(8); bar(B3)
// Both operands now staged exactly 2 phases before their drain point:
//  issued ph2(t), drained by vmcnt(8) at end of ph2(t+1)  (~2 block-phases
//  of wall time at 2 blocks/CU >= HBM latency).
// Slot safety: A(t+2)/B(t+2) overwrite slot t, whose ds_reads all happened
// in ph1(t) -- separated from the stage issue by bar(B2) + a 16-MFMA
// cluster + >=180cy load flight (same margin r4 validated). Tail clamp
// re-writes identical bytes (benign; validated r2/r4).
// vmcnt ledger: end ph2(t) queue = [A(t+1),B(t+1), A(t+2),B(t+2)] = 16
//  -> vmcnt(8) drains exactly A(t+1),B(t+1) needed for ph1(t+1).
//
// K axis concatenates two operand pairs: tiles [0,nts) -> (A0,B0), tiles
// [nts,nt) -> (A1,B1) (fuses X@Wih + Hp@Whh, K=6400, single prologue).
// ---------------------------------------------------------------------------
__device__ __forceinline__ void kloop128(
    const u16* __restrict__ A0, const u16* __restrict__ A1,
    const u16* __restrict__ B0, const u16* __restrict__ B1,
    int nts, int nt, int m_base, int n_base,
    u16* sA, u16* sB, floatx4 (&acc)[4][4])
{
    const int tid = threadIdx.x;
    const int wave = tid >> 6, lane = tid & 63;
    // staging lane geometry (pre-swizzled global source, linear LDS dest)
    const int r = tid >> 2, c = tid & 3;
    const int swe = (c ^ ((r >> 1) & 3)) << 3;
    // fragment ds_read offsets (elems), same verified swizzle
    const int frow = lane & 15, fch = lane >> 4;
    const int wrow0 = (wave >> 1) * 64, wcol0 = (wave & 1) * 64;
    int aoff[4], boff[4];
    #pragma unroll
    for (int mi = 0; mi < 4; ++mi) {
        int row = wrow0 + mi * 16 + frow;
        aoff[mi] = row * 32 + ((fch ^ ((row >> 1) & 3)) << 3);
    }
    #pragma unroll
    for (int ni = 0; ni < 4; ++ni) {
        int row = wcol0 + ni * 16 + frow;
        boff[ni] = row * 32 + ((fch ^ ((row >> 1) & 3)) << 3);
    }

    // stage one full K-tile (2 slabs x 2 row-halves = 4 gld_lds16)
    auto stA = [&](int tau) {
        int tc = tau < nt ? tau : nt - 1;          // tail clamp (same-value rewrite)
        const u16* p = (tc < nts) ? A0 : A1;
        int k = ((tc < nts) ? tc : tc - nts) << 6;
        const u16* src = p + (size_t)(m_base + r) * H_DIM + swe + k;
        u16* dst = sA + (tc & 1) * 8192 + wave * 512;
        gld_lds16(src, dst);                               // slab0 rows 0-63
        gld_lds16(src + (size_t)64 * H_DIM, dst + 2048);   // slab0 rows 64-127
        gld_lds16(src + 32, dst + 4096);                   // slab1 rows 0-63
        gld_lds16(src + 32 + (size_t)64 * H_DIM, dst + 6144);
    };
    auto stB = [&](int tau) {
        int tc = tau < nt ? tau : nt - 1;
        const u16* p = (tc < nts) ? B0 : B1;
        int k = ((tc < nts) ? tc : tc - nts) << 6;
        const u16* src = p + (size_t)(n_base + r) * H_DIM + swe + k;
        u16* dst = sB + (tc & 1) * 8192 + wave * 512;
        gld_lds16(src, dst);
        gld_lds16(src + (size_t)64 * H_DIM, dst + 2048);
        gld_lds16(src + 32, dst + 4096);
        gld_lds16(src + 32 + (size_t)64 * H_DIM, dst + 6144);
    };

    // prologue: tiles 0 and 1 (16 loads); drain tile 0, leave tile 1 in flight.
    stA(0); stB(0); stA(1); stB(1);
    VMCNT8();
    bar_();

    for (int t = 0; t < nt; ++t) {
        const int bo = (t & 1) * 8192;
        short8 af[4][2], bfr[4][2];
        // ---- ph1: read ALL fragments of tile t (ni23 last) ----
        #pragma unroll
        for (int mi = 0; mi < 4; ++mi) {
            af[mi][0] = *(const short8*)(sA + bo + aoff[mi]);
            af[mi][1] = *(const short8*)(sA + bo + 4096 + aoff[mi]);
        }
        #pragma unroll
        for (int ni = 0; ni < 2; ++ni) {
            bfr[ni][0] = *(const short8*)(sB + bo + boff[ni]);
            bfr[ni][1] = *(const short8*)(sB + bo + 4096 + boff[ni]);
        }
        #pragma unroll
        for (int ni = 2; ni < 4; ++ni) {
            bfr[ni][0] = *(const short8*)(sB + bo + boff[ni]);
            bfr[ni][1] = *(const short8*)(sB + bo + 4096 + boff[ni]);
        }
        bar_();                                    // B1
        __builtin_amdgcn_s_setprio(1);
        #pragma unroll
        for (int mi = 0; mi < 4; ++mi)
            #pragma unroll
            for (int ni = 0; ni < 2; ++ni) {
                acc[mi][ni] = __builtin_amdgcn_mfma_f32_16x16x32_bf16(af[mi][0], bfr[ni][0], acc[mi][ni], 0, 0, 0);
                acc[mi][ni] = __builtin_amdgcn_mfma_f32_16x16x32_bf16(af[mi][1], bfr[ni][1], acc[mi][ni], 0, 0, 0);
            }
        __builtin_amdgcn_s_setprio(0);
        bar_();                                    // B2
        // ---- ph2: stage both next-next tiles, then finish MFMA ----
        stA(t + 2);
        stB(t + 2);
        __builtin_amdgcn_s_setprio(1);
        #pragma unroll
        for (int mi = 0; mi < 4; ++mi)
            #pragma unroll
            for (int ni = 2; ni < 4; ++ni) {
                acc[mi][ni] = __builtin_amdgcn_mfma_f32_16x16x32_bf16(af[mi][0], bfr[ni][0], acc[mi][ni], 0, 0, 0);
                acc[mi][ni] = __builtin_amdgcn_mfma_f32_16x16x32_bf16(af[mi][1], bfr[ni][1], acc[mi][ni], 0, 0, 0);
            }
        __builtin_amdgcn_s_setprio(0);
        VMCNT8();                  // tile t+1 fully resident after this
        bar_();                                    // B3
    }
}

// ---------------------------------------------------------------------------
// Phase A. grid = (M-tiles=20, N-tiles=25, 3); x fastest => concurrent blocks
// share the same W-tile (L2/L3 reuse). z slowest: fused K=6400 gates first.
// Output PACKED fragment-major (round-0 layout):
//   tile(nbi*20+bmi)*16384 + wave*4096 + (mi*4+ni)*256 + lane*4 + j
// ---------------------------------------------------------------------------
__global__ __launch_bounds__(256) void gru_gemm_a(
    const u16* __restrict__ Xbf, const u16* __restrict__ Hpbf,
    const u16* __restrict__ Wih, const u16* __restrict__ Whh,
    const float* __restrict__ b_ih, const float* __restrict__ b_hh,
    u16* __restrict__ Rb, u16* __restrict__ Zb, u16* __restrict__ Gb) {
    __shared__ u16 sA[16384], sB[16384];   // 64 KB total -> 2 blocks/CU
    floatx4 acc[4][4];
    #pragma unroll
    for (int i = 0; i < 4; ++i)
        #pragma unroll
        for (int j = 0; j < 4; ++j) acc[i][j] = (floatx4){0.f, 0.f, 0.f, 0.f};
    const int g = blockIdx.z;
    const int bmi = blockIdx.x, nbi = blockIdx.y;
    const int m_base = bmi * 128, nb = nbi * 128;
    const size_t gstride = (size_t)H_DIM * H_DIM;
    if (g < 2) {
        kloop128(Xbf, Hpbf, Wih + g * gstride, Whh + g * gstride, 50, 100, m_base, nb, sA, sB, acc);
    } else {
        kloop128(Hpbf, Hpbf, Whh + 2 * gstride, Whh + 2 * gstride, 50, 50, m_base, nb, sA, sB, acc);
    }
    u16* outp = (g == 0) ? Rb : (g == 1) ? Zb : Gb;
    const int lane = threadIdx.x & 63, wave = threadIdx.x >> 6;
    const int wcol0 = (wave & 1) * 64, cc = lane & 15;
    const size_t tbase = (size_t)(nbi * 20 + bmi) * 16384 + wave * 4096 + lane * 4;
    #pragma unroll
    for (int ni = 0; ni < 4; ++ni) {
        int col = nb + wcol0 + ni * 16 + cc;
        float bsum;
        if (g == 0)      bsum = b_ih[col] + b_hh[col];
        else if (g == 1) bsum = b_ih[H_DIM + col] + b_hh[H_DIM + col];
        else             bsum = b_hh[2 * H_DIM + col];
        #pragma unroll
        for (int mi = 0; mi < 4; ++mi) {
            short4v o;
            #pragma unroll
            for (int j = 0; j < 4; ++j) {
                float v = acc[mi][ni][j] + bsum;
                if (g < 2) v = sigmoidf_(v);
                o[j] = (short)f2bf(v);
            }
            *(short4v*)(outp + tbase + (mi * 4 + ni) * 256) = o;
        }
    }
}

// ---------------------------------------------------------------------------
// Phase B: gx_n GEMM + GRU combine. Reads packed r/z/ghn' (8B coalesced),
// fast tanh, writes Hn row-major bf16.
// ---------------------------------------------------------------------------
__global__ __launch_bounds__(256) void gru_gemm_b(
    const u16* __restrict__ Xbf, const u16* __restrict__ Wih,
    const u16* __restrict__ Rb, const u16* __restrict__ Zb, const u16* __restrict__ Gb,
    const float* __restrict__ b_ih,
    const float* __restrict__ hprev, u16* __restrict__ Hn) {
    __shared__ u16 sA[16384], sB[16384];
    floatx4 acc[4][4];
    #pragma unroll
    for (int i = 0; i < 4; ++i)
        #pragma unroll
        for (int j = 0; j < 4; ++j) acc[i][j] = (floatx4){0.f, 0.f, 0.f, 0.f};
    const int bmi = blockIdx.x, nbi = blockIdx.y;
    const int m_base = bmi * 128, nb = nbi * 128;
    const u16* Wn = Wih + (size_t)2 * H_DIM * H_DIM;
    kloop128(Xbf, Xbf, Wn, Wn, 50, 50, m_base, nb, sA, sB, acc);
    const int lane = threadIdx.x & 63, wave = threadIdx.x >> 6;
    const int wrow0 = (wave >> 1) * 64, wcol0 = (wave & 1) * 64;
    const int quad = lane >> 4, cc = lane & 15;
    const size_t tbase = (size_t)(nbi * 20 + bmi) * 16384 + wave * 4096 + lane * 4;
    #pragma unroll
    for (int ni = 0; ni < 4; ++ni) {
        int col = nb + wcol0 + ni * 16 + cc;
        float bin_ = b_ih[2 * H_DIM + col];
        #pragma unroll
        for (int mi = 0; mi < 4; ++mi) {
            size_t pidx = tbase + (mi * 4 + ni) * 256;
            short4v rv = *(const short4v*)(Rb + pidx);
            short4v zv = *(const short4v*)(Zb + pidx);
            short4v gv = *(const short4v*)(Gb + pidx);
            int rw = m_base + wrow0 + mi * 16 + quad * 4;
            #pragma unroll
            for (int j = 0; j < 4; ++j) {
                float r = bf2f((u16)rv[j]);
                float z = bf2f((u16)zv[j]);
                float gh = bf2f((u16)gv[j]);
                float n = fast_tanh(acc[mi][ni][j] + bin_ + r * gh);
                size_t idx = (size_t)(rw + j) * H_DIM + col;
                float h = hprev[idx];
                Hn[idx] = f2bf((1.f - z) * n + z * h);
            }
        }
    }
}

// ---------------------------------------------------------------------------
// fc1: O = dropout(relu(Hn@fc1_w^T + b)). 128x64 tile bf16 MFMA (round-0).
// ---------------------------------------------------------------------------
__global__ __launch_bounds__(256) void fc1_k(
    const u16* __restrict__ Hn, const u16* __restrict__ Wb,
    const float* __restrict__ bias, const float* __restrict__ u2,
    const float* __restrict__ pl2, float* __restrict__ O) {
    __shared__ u16 sA[4096], sB[2048];
    floatx4 acc[4][2];
    #pragma unroll
    for (int i = 0; i < 4; ++i) { acc[i][0] = (floatx4){0.f,0.f,0.f,0.f}; acc[i][1] = (floatx4){0.f,0.f,0.f,0.f}; }
    const int tid = threadIdx.x;
    const int wave = tid >> 6, lane = tid & 63;
    const int m_base = blockIdx.y * 128, nb = blockIdx.x * 64;
    const int r = tid >> 2, c = tid & 3;
    const int swe = (c ^ ((r >> 1) & 3)) << 3;
    const u16* Ag = Hn + (size_t)(m_base + r) * H_DIM + swe;
    const u16* Bg = Wb + (size_t)(nb + r) * H_DIM + swe;
    u16* sA0 = sA + wave * 512;
    u16* sB0 = sB + wave * 512;
    const int frow = lane & 15, fch = lane >> 4;
    const int wrow0 = (wave >> 1) * 64, wcol0 = (wave & 1) * 32;
    int aoff[4], boff[2];
    #pragma unroll
    for (int mi = 0; mi < 4; ++mi) {
        int row = wrow0 + mi * 16 + frow;
        aoff[mi] = row * 32 + ((fch ^ ((row >> 1) & 3)) << 3);
    }
    #pragma unroll
    for (int ni = 0; ni < 2; ++ni) {
        int row = wcol0 + ni * 16 + frow;
        boff[ni] = row * 32 + ((fch ^ ((row >> 1) & 3)) << 3);
    }
    for (int kk = 0; kk < 100; ++kk) {
        __syncthreads();
        gld_lds16(Ag + kk * 32, sA0);
        gld_lds16(Ag + kk * 32 + (size_t)64 * H_DIM, sA0 + 2048);
        gld_lds16(Bg + kk * 32, sB0);
        __syncthreads();
        short8 af[4], bfr[2];
        #pragma unroll
        for (int mi = 0; mi < 4; ++mi) af[mi] = *(const short8*)(sA + aoff[mi]);
        #pragma unroll
        for (int ni = 0; ni < 2; ++ni) bfr[ni] = *(const short8*)(sB + boff[ni]);
        #pragma unroll
        for (int mi = 0; mi < 4; ++mi)
            #pragma unroll
            for (int ni = 0; ni < 2; ++ni)
                acc[mi][ni] = __builtin_amdgcn_mfma_f32_16x16x32_bf16(af[mi], bfr[ni], acc[mi][ni], 0, 0, 0);
    }
    float p = sigmoidf_(pl2[0]);
    float lp = __logf(p) - log1pf(-p);
    float inv = 1.0f / (1.0f - p);
    const int quad = lane >> 4, cc = lane & 15;
    #pragma unroll
    for (int ni = 0; ni < 2; ++ni) {
        int col = nb + wcol0 + ni * 16 + cc;
        float bcol = bias[col];
        #pragma unroll
        for (int mi = 0; mi < 4; ++mi) {
            int rw = m_base + wrow0 + mi * 16 + quad * 4;
            #pragma unroll
            for (int j = 0; j < 4; ++j) {
                size_t idx = (size_t)(rw + j) * OUT1 + col;
                float v = fmaxf(acc[mi][ni][j] + bcol, 0.f);
                float u = u2[idx];
                float z = sigmoidf_((lp + __logf(u) - log1pf(-u)) * TEMP_INV);
                O[idx] = v * (1.0f - z) * inv;
            }
        }
    }
}

// ---------------------------------------------------------------------------
// fp32 -> bf16 conversion, 8 elts/thread
// ---------------------------------------------------------------------------
__global__ void cvt_bf16_k(const float* __restrict__ src, u16* __restrict__ dst, int n8) {
    int i = blockIdx.x * 256 + threadIdx.x;
    if (i >= n8) return;
    float4 v0 = *((const float4*)src + 2 * (size_t)i);
    float4 v1 = *((const float4*)src + 2 * (size_t)i + 1);
    short8 o;
    o[0] = (short)f2bf(v0.x); o[1] = (short)f2bf(v0.y);
    o[2] = (short)f2bf(v0.z); o[3] = (short)f2bf(v0.w);
    o[4] = (short)f2bf(v1.x); o[5] = (short)f2bf(v1.y);
    o[6] = (short)f2bf(v1.z); o[7] = (short)f2bf(v1.w);
    *(short8*)(dst + 8 * (size_t)i) = o;
}

// ---------------------------------------------------------------------------
// prep: system model + input concat (fp32, exact)
// ---------------------------------------------------------------------------
__global__ void prep_k(const float* __restrict__ y_t, const float* __restrict__ xfp,
                       const float* __restrict__ xfpp, const float* __restrict__ yprev,
                       const float* __restrict__ dxp, const float* __restrict__ Fm,
                       const float* __restrict__ Hm,
                       float* __restrict__ xpred, float* __restrict__ resid,
                       float* __restrict__ inp) {
    int b = threadIdx.x;
    float xrow[SD], xp[SD];
    for (int k = 0; k < SD; ++k) xrow[k] = xfp[b * SD + k];
    for (int s = 0; s < SD; ++s) {
        float acc = 0.f;
        for (int k = 0; k < SD; ++k) acc += xrow[k] * Fm[s * SD + k];
        xp[s] = tanhf(acc);
        xpred[b * SD + s] = xp[s];
    }
    float res[OD];
    for (int o = 0; o < OD; ++o) {
        float acc = 0.f;
        for (int s = 0; s < SD; ++s) acc += xp[s] * Hm[o * SD + s];
        res[o] = y_t[b * OD + o] - acc;
        resid[b * OD + o] = res[o];
    }
    float* ir = inp + b * IN_DIM;
    for (int k = 0; k < SD; ++k) ir[k] = dxp[b * SD + k];
    for (int o = 0; o < OD; ++o) ir[SD + o] = res[o];
    for (int k = 0; k < SD; ++k) ir[SD + OD + k] = xrow[k] - xfpp[b * SD + k];
    for (int o = 0; o < OD; ++o) ir[SD + OD + SD + o] = yprev[b * OD + o];
}

__global__ void fc_in_k(const float* __restrict__ inp, const float* __restrict__ w,
                        const float* __restrict__ bias, float* __restrict__ a) {
    int b = blockIdx.x;
    __shared__ float row[IN_DIM];
    int t = threadIdx.x;
    if (t < IN_DIM) row[t] = inp[b * IN_DIM + t];
    __syncthreads();
    for (int j = t; j < H_DIM; j += 256) {
        float s = bias[j];
        const float* wr = w + j * IN_DIM;
        #pragma unroll 8
        for (int k = 0; k < IN_DIM; ++k) s += row[k] * wr[k];
        a[b * H_DIM + j] = fmaxf(s, 0.f);
    }
}

// X (bf16) = concrete_dropout(a, u1, p1)
__global__ void dropx_k(const float* __restrict__ a, const float* __restrict__ u1,
                        const float* __restrict__ pl1, u16* __restrict__ X) {
    int idx_in = blockIdx.x * 256 + threadIdx.x;
    int i = blockIdx.y;
    float p = sigmoidf_(pl1[0]);
    float lp = __logf(p) - log1pf(-p);
    float inv = 1.0f / (1.0f - p);
    size_t gidx = (size_t)i * (B_DIM * H_DIM) + idx_in;
    float u = u1[gidx];
    float z = sigmoidf_((lp + __logf(u) - log1pf(-u)) * TEMP_INV);
    X[gidx] = f2bf(a[idx_in] * (1.0f - z) * inv);
}

// K = o @ fc2_w^T + b; xf = x_pred + K @ residual
__global__ void fc2_corr_k(const float* __restrict__ O, const float* __restrict__ w,
                           const float* __restrict__ bias, const float* __restrict__ resid,
                           const float* __restrict__ xpred, float* __restrict__ xf_ens) {
    int row = blockIdx.x;
    int b = row & (B_DIM - 1);
    __shared__ __align__(16) float orow[OUT1];
    int t = threadIdx.x;
    for (int k = t; k < OUT1; k += 128) orow[k] = O[(size_t)row * OUT1 + k];
    __syncthreads();
    int s = t >> 3, oo = t & 7;
    const float* wr = w + (s * OD + oo) * OUT1;
    float sum = 0.f;
    for (int k = 0; k < OUT1; k += 4) {
        float4 ov = *(const float4*)&orow[k];
        float4 wv = *(const float4*)&wr[k];
        sum += ov.x * wv.x + ov.y * wv.y + ov.z * wv.z + ov.w * wv.w;
    }
    sum += bias[s * OD + oo];
    float v = sum * resid[b * OD + oo];
    v += __shfl_down(v, 4, 8);
    v += __shfl_down(v, 2, 8);
    v += __shfl_down(v, 1, 8);
    if (oo == 0) xf_ens[row * SD + s] = xpred[b * SD + s] + v;
}

__global__ void stats_k(const float* __restrict__ xf_ens, float* __restrict__ out) {
    int b = blockIdx.x;
    __shared__ float xf[S_ENS][SD];
    __shared__ float mean[SD];
    int t = threadIdx.x;
    if (t < S_ENS * SD) {
        int s = t >> 4, k = t & 15;
        xf[s][k] = xf_ens[s * (B_DIM * SD) + b * SD + k];
    }
    __syncthreads();
    if (t < SD) {
        float m = 0.f;
        for (int s = 0; s < S_ENS; ++s) m += xf[s][t];
        m *= (1.0f / S_ENS);
        mean[t] = m;
        out[b * SD + t] = m;
    }
    __syncthreads();
    int i = t >> 4, j = t & 15;
    float p = 0.f;
    for (int s = 0; s < S_ENS; ++s) p += (xf[s][i] - mean[i]) * (xf[s][j] - mean[j]);
    out[B_DIM * SD + b * 256 + t] = p * (1.0f / S_ENS);
}

__global__ void sumsq_k(const float* __restrict__ w, int n, float* __restrict__ accum) {
    float s = 0.f;
    for (int i = blockIdx.x * blockDim.x + threadIdx.x; i < n; i += gridDim.x * blockDim.x) {
        float v = w[i];
        s += v * v;
    }
    #pragma unroll
    for (int d = 32; d >= 1; d >>= 1) s += __shfl_down(s, d, 64);
    __shared__ float red[4];
    int lane = threadIdx.x & 63, wv = threadIdx.x >> 6;
    if (lane == 0) red[wv] = s;
    __syncthreads();
    if (threadIdx.x == 0) atomicAdd(accum, red[0] + red[1] + red[2] + red[3]);
}

__global__ void write_reg_k(const float* __restrict__ sums, const float* __restrict__ pl1,
                            const float* __restrict__ pl2, float* __restrict__ out) {
    int t = threadIdx.x;
    float p1 = sigmoidf_(pl1[0]);
    float p2 = sigmoidf_(pl2[0]);
    float ent1 = p1 * logf(p1) + (1.f - p1) * log1pf(-p1);
    float ent2 = p2 * logf(p2) + (1.f - p2) * log1pf(-p2);
    float reg = sums[0] / (1.f - p1) + (float)H_DIM * ent1
              + sums[1] / (1.f - p2) + (float)OUT1 * ent2;
    if (t < S_ENS) out[B_DIM * SD + B_DIM * SD * SD + t] = reg;
}

// ---------------------------------------------------------------------------
extern "C" void kernel_launch(void* const* d_in, const int* in_sizes, int n_in,
                              void* d_out, int out_size, void* d_ws, size_t ws_size,
                              hipStream_t stream) {
    const float* y_t     = (const float*)d_in[0];
    const float* xfp     = (const float*)d_in[1];
    const float* xfpp    = (const float*)d_in[2];
    const float* yprev   = (const float*)d_in[3];
    const float* dxp     = (const float*)d_in[4];
    const float* hprev   = (const float*)d_in[5];
    const float* Fm      = (const float*)d_in[6];
    const float* Hm      = (const float*)d_in[7];
    const float* fc_in_w = (const float*)d_in[8];
    const float* fc_in_b = (const float*)d_in[9];
    const float* W_ih    = (const float*)d_in[10];
    const float* W_hh    = (const float*)d_in[11];
    const float* b_ih    = (const float*)d_in[12];
    const float* b_hh    = (const float*)d_in[13];
    const float* fc1_w   = (const float*)d_in[14];
    const float* fc1_b   = (const float*)d_in[15];
    const float* fc2_w   = (const float*)d_in[16];
    const float* fc2_b   = (const float*)d_in[17];
    const float* pl1     = (const float*)d_in[18];
    const float* pl2     = (const float*)d_in[19];
    const float* u1      = (const float*)d_in[20];
    const float* u2      = (const float*)d_in[21];
    float* out = (float*)d_out;
    char* ws = (char*)d_ws;

    const size_t SZ_W    = (size_t)3 * H_DIM * H_DIM * 2;
    const size_t SZ_MH   = (size_t)M_ROWS * H_DIM * 2;
    size_t off = 0;
    u16* Wihbf  = (u16*)(ws + off); off += SZ_W;
    u16* Whhbf  = (u16*)(ws + off); off += SZ_W;
    u16* Rb     = (u16*)(ws + off); off += SZ_MH;
    u16* Zb     = (u16*)(ws + off); off += SZ_MH;
    u16* Gb     = (u16*)(ws + off); off += SZ_MH;
    u16* Xbf    = (u16*)(ws + off); off += SZ_MH;
    u16* Hpbf   = (u16*)(ws + off); off += SZ_MH;
    u16* Hnbf   = Hpbf;                       // alias: Hpbf dead before phase-B writes
    u16* fc1wbf = (u16*)(ws + off); off += (size_t)OUT1 * H_DIM * 2;
    float* O_buf   = (float*)(ws + off); off += (size_t)M_ROWS * OUT1 * 4;
    float* a_buf   = (float*)(ws + off); off += (size_t)B_DIM * H_DIM * 4;
    float* xf_buf  = (float*)(ws + off); off += (size_t)M_ROWS * SD * 4;
    float* xpred_b = (float*)(ws + off); off += (size_t)B_DIM * SD * 4;
    float* res_b   = (float*)(ws + off); off += (size_t)B_DIM * OD * 4;
    float* inp_b   = (float*)(ws + off); off += (size_t)B_DIM * IN_DIM * 4;
    float* sums_b  = (float*)(ws + off); off += 256;

    hipMemsetAsync(sums_b, 0, 2 * sizeof(float), stream);

    prep_k<<<1, 256, 0, stream>>>(y_t, xfp, xfpp, yprev, dxp, Fm, Hm, xpred_b, res_b, inp_b);
    fc_in_k<<<B_DIM, 256, 0, stream>>>(inp_b, fc_in_w, fc_in_b, a_buf);
    dropx_k<<<dim3(B_DIM * H_DIM / 256, S_ENS), 256, 0, stream>>>(a_buf, u1, pl1, Xbf);

    cvt_bf16_k<<<15000, 256, 0, stream>>>(W_ih, Wihbf, 3 * H_DIM * H_DIM / 8);
    cvt_bf16_k<<<15000, 256, 0, stream>>>(W_hh, Whhbf, 3 * H_DIM * H_DIM / 8);
    cvt_bf16_k<<<4000, 256, 0, stream>>>(hprev, Hpbf, M_ROWS * H_DIM / 8);
    cvt_bf16_k<<<800, 256, 0, stream>>>(fc1_w, fc1wbf, OUT1 * H_DIM / 8);

    // GRU: 128x128 tiles, BK=64 dbuf, v2 deep-prefetch 2-phase K-loop.
    gru_gemm_a<<<dim3(M_ROWS / 128, H_DIM / 128, 3), 256, 0, stream>>>(
        Xbf, Hpbf, Wihbf, Whhbf, b_ih, b_hh, Rb, Zb, Gb);
    gru_gemm_b<<<dim3(M_ROWS / 128, H_DIM / 128), 256, 0, stream>>>(
        Xbf, Wihbf, Rb, Zb, Gb, b_ih, hprev, Hnbf);

    fc1_k<<<dim3(OUT1 / 64, M_ROWS / 128), 256, 0, stream>>>(Hnbf, fc1wbf, fc1_b, u2, pl2, O_buf);

    fc2_corr_k<<<M_ROWS, 128, 0, stream>>>(O_buf, fc2_w, fc2_b, res_b, xpred_b, xf_buf);
    stats_k<<<B_DIM, 256, 0, stream>>>(xf_buf, out);
    sumsq_k<<<256, 256, 0, stream>>>(fc_in_w, H_DIM * IN_DIM, sums_b);
    sumsq_k<<<1024, 256, 0, stream>>>(fc1_w, OUT1 * H_DIM, sums_b + 1);
    write_reg_k<<<1, 64, 0, stream>>>(sums_b, pl1, pl2, out);
}

// Round 6
// 931.769 us; speedup vs baseline: 1.1652x; 1.0340x over previous
//
#include <hip/hip_runtime.h>
#include <hip/hip_bf16.h>
#include <math.h>

// Problem constants
#define S_ENS 10
#define B_DIM 256
#define SD 16
#define OD 8
#define H_DIM 3200
#define OUT1 512
#define IN_DIM 48
#define M_ROWS (S_ENS * B_DIM)     // 2560
#define TEMP_INV 10.0f

typedef unsigned short u16;
typedef __attribute__((ext_vector_type(8))) short short8;
typedef __attribute__((ext_vector_type(4))) short short4v;   // 8B packed bf16x4
typedef __attribute__((ext_vector_type(4))) float floatx4;

__device__ __forceinline__ float sigmoidf_(float x) { return 1.0f / (1.0f + __expf(-x)); }
__device__ __forceinline__ float fast_tanh(float x) {
    x = fminf(fmaxf(x, -15.f), 15.f);
    float e = __expf(2.f * x);
    return (e - 1.f) / (e + 1.f);
}

// fp32 -> bf16 round-to-nearest-even
__device__ __forceinline__ u16 f2bf(float f) {
    union { float f; unsigned u; } v; v.f = f;
    unsigned u = v.u + 0x7fffu + ((v.u >> 16) & 1u);
    return (u16)(u >> 16);
}
__device__ __forceinline__ float bf2f(u16 h) {
    union { unsigned u; float f; } v; v.u = ((unsigned)h) << 16;
    return v.f;
}

// async global->LDS, 16B per lane. LDS dest: wave-uniform base + lane*16.
__device__ __forceinline__ void gld_lds16(const u16* g, u16* l) {
    __builtin_amdgcn_global_load_lds((const __attribute__((address_space(1))) void*)g,
                                     (__attribute__((address_space(3))) void*)l, 16, 0, 0);
}

// Raw barrier with compiler-level memory fence + sched pin (NO auto vmcnt(0)).
__device__ __forceinline__ void bar_() {
    __builtin_amdgcn_sched_barrier(0);
    asm volatile("" ::: "memory");
    __builtin_amdgcn_s_barrier();
    asm volatile("" ::: "memory");
    __builtin_amdgcn_sched_barrier(0);
}
#define VMCNT8() asm volatile("s_waitcnt vmcnt(8)" ::: "memory")
#define LGKM0()  do { __builtin_amdgcn_sched_barrier(0); \
                      asm volatile("s_waitcnt lgkmcnt(0)" ::: "memory"); \
                      __builtin_amdgcn_sched_barrier(0); } while (0)

// ---------------------------------------------------------------------------
// 128x128-tile bf16 MFMA K-loop, BK=64 (2x K=32 slabs), double-buffered,
// 4 waves (256 thr), 64 KB LDS -> 2 blocks/CU.
// Chunk-XOR swizzled LDS (verified: SQ_LDS_BANK_CONFLICT == 0).
//
// v3 schedule (r5 post-mortem: SYNC-bound, 6 barrier events/tile-pair ate
// ~1500cy): 2 barriers per K-tile, one fat 32-MFMA cluster:
//   reads(t) all 16 frags; lgkmcnt(0); bar(B1);
//   stage A(t+2)+B(t+2) [8 gld]; setprio1; 32 MFMA; setprio0; VMCNT(8); bar(B2)
// Safety is now DETERMINISTIC (not timing-based): lgkmcnt(0) before B1 means
// every wave's ds_reads of slot t are complete chip-wide before any wave can
// issue the slot-t-overwriting gld after B1.
// vmcnt ledger: after stage(t+2): in-flight = 8(t+1) + 8(t+2) = 16;
// vmcnt(8) at tile end drains t+1 exactly. Prologue: st(0),st(1) = 16;
// vmcnt(8) -> t0 resident. Tail clamp re-writes identical bytes (benign;
// validated r2/r4/r5).
//
// K axis concatenates two operand pairs: tiles [0,nts) -> (A0,B0), tiles
// [nts,nt) -> (A1,B1) (fuses X@Wih + Hp@Whh, K=6400, single prologue).
// ---------------------------------------------------------------------------
__device__ __forceinline__ void kloop128(
    const u16* __restrict__ A0, const u16* __restrict__ A1,
    const u16* __restrict__ B0, const u16* __restrict__ B1,
    int nts, int nt, int m_base, int n_base,
    u16* sA, u16* sB, floatx4 (&acc)[4][4])
{
    const int tid = threadIdx.x;
    const int wave = tid >> 6, lane = tid & 63;
    // staging lane geometry (pre-swizzled global source, linear LDS dest)
    const int r = tid >> 2, c = tid & 3;
    const int swe = (c ^ ((r >> 1) & 3)) << 3;
    // fragment ds_read offsets (elems), same verified swizzle
    const int frow = lane & 15, fch = lane >> 4;
    const int wrow0 = (wave >> 1) * 64, wcol0 = (wave & 1) * 64;
    int aoff[4], boff[4];
    #pragma unroll
    for (int mi = 0; mi < 4; ++mi) {
        int row = wrow0 + mi * 16 + frow;
        aoff[mi] = row * 32 + ((fch ^ ((row >> 1) & 3)) << 3);
    }
    #pragma unroll
    for (int ni = 0; ni < 4; ++ni) {
        int row = wcol0 + ni * 16 + frow;
        boff[ni] = row * 32 + ((fch ^ ((row >> 1) & 3)) << 3);
    }

    // stage one full K-tile (2 slabs x 2 row-halves = 4 gld_lds16)
    auto stA = [&](int tau) {
        int tc = tau < nt ? tau : nt - 1;          // tail clamp (same-value rewrite)
        const u16* p = (tc < nts) ? A0 : A1;
        int k = ((tc < nts) ? tc : tc - nts) << 6;
        const u16* src = p + (size_t)(m_base + r) * H_DIM + swe + k;
        u16* dst = sA + (tc & 1) * 8192 + wave * 512;
        gld_lds16(src, dst);                               // slab0 rows 0-63
        gld_lds16(src + (size_t)64 * H_DIM, dst + 2048);   // slab0 rows 64-127
        gld_lds16(src + 32, dst + 4096);                   // slab1 rows 0-63
        gld_lds16(src + 32 + (size_t)64 * H_DIM, dst + 6144);
    };
    auto stB = [&](int tau) {
        int tc = tau < nt ? tau : nt - 1;
        const u16* p = (tc < nts) ? B0 : B1;
        int k = ((tc < nts) ? tc : tc - nts) << 6;
        const u16* src = p + (size_t)(n_base + r) * H_DIM + swe + k;
        u16* dst = sB + (tc & 1) * 8192 + wave * 512;
        gld_lds16(src, dst);
        gld_lds16(src + (size_t)64 * H_DIM, dst + 2048);
        gld_lds16(src + 32, dst + 4096);
        gld_lds16(src + 32 + (size_t)64 * H_DIM, dst + 6144);
    };

    // prologue: tiles 0 and 1 (16 loads); drain tile 0, leave tile 1 in flight.
    stA(0); stB(0); stA(1); stB(1);
    VMCNT8();
    bar_();

    for (int t = 0; t < nt; ++t) {
        const int bo = (t & 1) * 8192;
        short8 af[4][2], bfr[4][2];
        // ---- read ALL fragments of tile t ----
        #pragma unroll
        for (int mi = 0; mi < 4; ++mi) {
            af[mi][0] = *(const short8*)(sA + bo + aoff[mi]);
            af[mi][1] = *(const short8*)(sA + bo + 4096 + aoff[mi]);
        }
        #pragma unroll
        for (int ni = 0; ni < 4; ++ni) {
            bfr[ni][0] = *(const short8*)(sB + bo + boff[ni]);
            bfr[ni][1] = *(const short8*)(sB + bo + 4096 + boff[ni]);
        }
        LGKM0();                       // all reads of slot t complete...
        bar_();                        // ...chip-wide before any overwrite (B1)
        // ---- stage t+2 (overwrites slot t), then fat MFMA cluster ----
        stA(t + 2);
        stB(t + 2);
        __builtin_amdgcn_s_setprio(1);
        #pragma unroll
        for (int mi = 0; mi < 4; ++mi)
            #pragma unroll
            for (int ni = 0; ni < 4; ++ni) {
                acc[mi][ni] = __builtin_amdgcn_mfma_f32_16x16x32_bf16(af[mi][0], bfr[ni][0], acc[mi][ni], 0, 0, 0);
                acc[mi][ni] = __builtin_amdgcn_mfma_f32_16x16x32_bf16(af[mi][1], bfr[ni][1], acc[mi][ni], 0, 0, 0);
            }
        __builtin_amdgcn_s_setprio(0);
        VMCNT8();                      // tile t+1 fully resident after this
        bar_();                        // B2
    }
}

// ---------------------------------------------------------------------------
// Phase A. grid = (M-tiles=20, N-tiles=25, 3); x fastest => concurrent blocks
// share the same W-tile (L2/L3 reuse). z slowest: fused K=6400 gates first.
// Output PACKED fragment-major (round-0 layout):
//   tile(nbi*20+bmi)*16384 + wave*4096 + (mi*4+ni)*256 + lane*4 + j
// ---------------------------------------------------------------------------
__global__ __launch_bounds__(256) void gru_gemm_a(
    const u16* __restrict__ Xbf, const u16* __restrict__ Hpbf,
    const u16* __restrict__ Wih, const u16* __restrict__ Whh,
    const float* __restrict__ b_ih, const float* __restrict__ b_hh,
    u16* __restrict__ Rb, u16* __restrict__ Zb, u16* __restrict__ Gb) {
    __shared__ u16 sA[16384], sB[16384];   // 64 KB total -> 2 blocks/CU
    floatx4 acc[4][4];
    #pragma unroll
    for (int i = 0; i < 4; ++i)
        #pragma unroll
        for (int j = 0; j < 4; ++j) acc[i][j] = (floatx4){0.f, 0.f, 0.f, 0.f};
    const int g = blockIdx.z;
    const int bmi = blockIdx.x, nbi = blockIdx.y;
    const int m_base = bmi * 128, nb = nbi * 128;
    const size_t gstride = (size_t)H_DIM * H_DIM;
    if (g < 2) {
        kloop128(Xbf, Hpbf, Wih + g * gstride, Whh + g * gstride, 50, 100, m_base, nb, sA, sB, acc);
    } else {
        kloop128(Hpbf, Hpbf, Whh + 2 * gstride, Whh + 2 * gstride, 50, 50, m_base, nb, sA, sB, acc);
    }
    u16* outp = (g == 0) ? Rb : (g == 1) ? Zb : Gb;
    const int lane = threadIdx.x & 63, wave = threadIdx.x >> 6;
    const int wcol0 = (wave & 1) * 64, cc = lane & 15;
    const size_t tbase = (size_t)(nbi * 20 + bmi) * 16384 + wave * 4096 + lane * 4;
    #pragma unroll
    for (int ni = 0; ni < 4; ++ni) {
        int col = nb + wcol0 + ni * 16 + cc;
        float bsum;
        if (g == 0)      bsum = b_ih[col] + b_hh[col];
        else if (g == 1) bsum = b_ih[H_DIM + col] + b_hh[H_DIM + col];
        else             bsum = b_hh[2 * H_DIM + col];
        #pragma unroll
        for (int mi = 0; mi < 4; ++mi) {
            short4v o;
            #pragma unroll
            for (int j = 0; j < 4; ++j) {
                float v = acc[mi][ni][j] + bsum;
                if (g < 2) v = sigmoidf_(v);
                o[j] = (short)f2bf(v);
            }
            *(short4v*)(outp + tbase + (mi * 4 + ni) * 256) = o;
        }
    }
}

// ---------------------------------------------------------------------------
// Phase B: gx_n GEMM + GRU combine. Reads packed r/z/ghn' (8B coalesced),
// fast tanh, writes Hn row-major bf16.
// ---------------------------------------------------------------------------
__global__ __launch_bounds__(256) void gru_gemm_b(
    const u16* __restrict__ Xbf, const u16* __restrict__ Wih,
    const u16* __restrict__ Rb, const u16* __restrict__ Zb, const u16* __restrict__ Gb,
    const float* __restrict__ b_ih,
    const float* __restrict__ hprev, u16* __restrict__ Hn) {
    __shared__ u16 sA[16384], sB[16384];
    floatx4 acc[4][4];
    #pragma unroll
    for (int i = 0; i < 4; ++i)
        #pragma unroll
        for (int j = 0; j < 4; ++j) acc[i][j] = (floatx4){0.f, 0.f, 0.f, 0.f};
    const int bmi = blockIdx.x, nbi = blockIdx.y;
    const int m_base = bmi * 128, nb = nbi * 128;
    const u16* Wn = Wih + (size_t)2 * H_DIM * H_DIM;
    kloop128(Xbf, Xbf, Wn, Wn, 50, 50, m_base, nb, sA, sB, acc);
    const int lane = threadIdx.x & 63, wave = threadIdx.x >> 6;
    const int wrow0 = (wave >> 1) * 64, wcol0 = (wave & 1) * 64;
    const int quad = lane >> 4, cc = lane & 15;
    const size_t tbase = (size_t)(nbi * 20 + bmi) * 16384 + wave * 4096 + lane * 4;
    #pragma unroll
    for (int ni = 0; ni < 4; ++ni) {
        int col = nb + wcol0 + ni * 16 + cc;
        float bin_ = b_ih[2 * H_DIM + col];
        #pragma unroll
        for (int mi = 0; mi < 4; ++mi) {
            size_t pidx = tbase + (mi * 4 + ni) * 256;
            short4v rv = *(const short4v*)(Rb + pidx);
            short4v zv = *(const short4v*)(Zb + pidx);
            short4v gv = *(const short4v*)(Gb + pidx);
            int rw = m_base + wrow0 + mi * 16 + quad * 4;
            #pragma unroll
            for (int j = 0; j < 4; ++j) {
                float r = bf2f((u16)rv[j]);
                float z = bf2f((u16)zv[j]);
                float gh = bf2f((u16)gv[j]);
                float n = fast_tanh(acc[mi][ni][j] + bin_ + r * gh);
                size_t idx = (size_t)(rw + j) * H_DIM + col;
                float h = hprev[idx];
                Hn[idx] = f2bf((1.f - z) * n + z * h);
            }
        }
    }
}

// ---------------------------------------------------------------------------
// fc1: O = dropout(relu(Hn@fc1_w^T + b)). 128x64 tile bf16 MFMA (round-0).
// ---------------------------------------------------------------------------
__global__ __launch_bounds__(256) void fc1_k(
    const u16* __restrict__ Hn, const u16* __restrict__ Wb,
    const float* __restrict__ bias, const float* __restrict__ u2,
    const float* __restrict__ pl2, float* __restrict__ O) {
    __shared__ u16 sA[4096], sB[2048];
    floatx4 acc[4][2];
    #pragma unroll
    for (int i = 0; i < 4; ++i) { acc[i][0] = (floatx4){0.f,0.f,0.f,0.f}; acc[i][1] = (floatx4){0.f,0.f,0.f,0.f}; }
    const int tid = threadIdx.x;
    const int wave = tid >> 6, lane = tid & 63;
    const int m_base = blockIdx.y * 128, nb = blockIdx.x * 64;
    const int r = tid >> 2, c = tid & 3;
    const int swe = (c ^ ((r >> 1) & 3)) << 3;
    const u16* Ag = Hn + (size_t)(m_base + r) * H_DIM + swe;
    const u16* Bg = Wb + (size_t)(nb + r) * H_DIM + swe;
    u16* sA0 = sA + wave * 512;
    u16* sB0 = sB + wave * 512;
    const int frow = lane & 15, fch = lane >> 4;
    const int wrow0 = (wave >> 1) * 64, wcol0 = (wave & 1) * 32;
    int aoff[4], boff[2];
    #pragma unroll
    for (int mi = 0; mi < 4; ++mi) {
        int row = wrow0 + mi * 16 + frow;
        aoff[mi] = row * 32 + ((fch ^ ((row >> 1) & 3)) << 3);
    }
    #pragma unroll
    for (int ni = 0; ni < 2; ++ni) {
        int row = wcol0 + ni * 16 + frow;
        boff[ni] = row * 32 + ((fch ^ ((row >> 1) & 3)) << 3);
    }
    for (int kk = 0; kk < 100; ++kk) {
        __syncthreads();
        gld_lds16(Ag + kk * 32, sA0);
        gld_lds16(Ag + kk * 32 + (size_t)64 * H_DIM, sA0 + 2048);
        gld_lds16(Bg + kk * 32, sB0);
        __syncthreads();
        short8 af[4], bfr[2];
        #pragma unroll
        for (int mi = 0; mi < 4; ++mi) af[mi] = *(const short8*)(sA + aoff[mi]);
        #pragma unroll
        for (int ni = 0; ni < 2; ++ni) bfr[ni] = *(const short8*)(sB + boff[ni]);
        #pragma unroll
        for (int mi = 0; mi < 4; ++mi)
            #pragma unroll
            for (int ni = 0; ni < 2; ++ni)
                acc[mi][ni] = __builtin_amdgcn_mfma_f32_16x16x32_bf16(af[mi], bfr[ni], acc[mi][ni], 0, 0, 0);
    }
    float p = sigmoidf_(pl2[0]);
    float lp = __logf(p) - log1pf(-p);
    float inv = 1.0f / (1.0f - p);
    const int quad = lane >> 4, cc = lane & 15;
    #pragma unroll
    for (int ni = 0; ni < 2; ++ni) {
        int col = nb + wcol0 + ni * 16 + cc;
        float bcol = bias[col];
        #pragma unroll
        for (int mi = 0; mi < 4; ++mi) {
            int rw = m_base + wrow0 + mi * 16 + quad * 4;
            #pragma unroll
            for (int j = 0; j < 4; ++j) {
                size_t idx = (size_t)(rw + j) * OUT1 + col;
                float v = fmaxf(acc[mi][ni][j] + bcol, 0.f);
                float u = u2[idx];
                float z = sigmoidf_((lp + __logf(u) - log1pf(-u)) * TEMP_INV);
                O[idx] = v * (1.0f - z) * inv;
            }
        }
    }
}

// ---------------------------------------------------------------------------
// fused fp32 -> bf16 conversion for all 4 tensors (1 launch instead of 4)
// block ranges: [0,15000) W_ih, [15000,30000) W_hh, [30000,34000) hprev,
// [34000,34800) fc1_w. All segment sizes are exact multiples of 2048 elems.
// ---------------------------------------------------------------------------
__global__ void cvt4_k(const float* __restrict__ s0, u16* __restrict__ d0,
                       const float* __restrict__ s1, u16* __restrict__ d1,
                       const float* __restrict__ s2, u16* __restrict__ d2,
                       const float* __restrict__ s3, u16* __restrict__ d3) {
    int blk = blockIdx.x;
    const float* s; u16* d; size_t i;
    if (blk < 15000)      { s = s0; d = d0; i = (size_t)blk * 256 + threadIdx.x; }
    else if (blk < 30000) { s = s1; d = d1; i = (size_t)(blk - 15000) * 256 + threadIdx.x; }
    else if (blk < 34000) { s = s2; d = d2; i = (size_t)(blk - 30000) * 256 + threadIdx.x; }
    else                  { s = s3; d = d3; i = (size_t)(blk - 34000) * 256 + threadIdx.x; }
    float4 v0 = *((const float4*)s + 2 * i);
    float4 v1 = *((const float4*)s + 2 * i + 1);
    short8 o;
    o[0] = (short)f2bf(v0.x); o[1] = (short)f2bf(v0.y);
    o[2] = (short)f2bf(v0.z); o[3] = (short)f2bf(v0.w);
    o[4] = (short)f2bf(v1.x); o[5] = (short)f2bf(v1.y);
    o[6] = (short)f2bf(v1.z); o[7] = (short)f2bf(v1.w);
    *(short8*)(d + 8 * i) = o;
}

// ---------------------------------------------------------------------------
// fused prep (system model, exact fp32) + fc_in: one block per batch element.
// ---------------------------------------------------------------------------
__global__ void prep_fcin_k(const float* __restrict__ y_t, const float* __restrict__ xfp,
                            const float* __restrict__ xfpp, const float* __restrict__ yprev,
                            const float* __restrict__ dxp, const float* __restrict__ Fm,
                            const float* __restrict__ Hm,
                            const float* __restrict__ w, const float* __restrict__ bias,
                            float* __restrict__ xpred, float* __restrict__ resid,
                            float* __restrict__ a) {
    int b = blockIdx.x;
    int t = threadIdx.x;
    __shared__ float row[IN_DIM];
    __shared__ float xps[SD];
    if (t < SD) {
        float acc = 0.f;
        for (int k = 0; k < SD; ++k) acc += xfp[b * SD + k] * Fm[t * SD + k];
        float xp = tanhf(acc);
        xps[t] = xp;
        xpred[b * SD + t] = xp;
        row[t] = dxp[b * SD + t];
        row[SD + OD + t] = xfp[b * SD + t] - xfpp[b * SD + t];
    }
    __syncthreads();
    if (t < OD) {
        float acc = 0.f;
        for (int s = 0; s < SD; ++s) acc += xps[s] * Hm[t * SD + s];
        float res = y_t[b * OD + t] - acc;
        resid[b * OD + t] = res;
        row[SD + t] = res;
        row[SD + OD + SD + t] = yprev[b * OD + t];
    }
    __syncthreads();
    for (int j = t; j < H_DIM; j += 256) {
        float s = bias[j];
        const float* wr = w + j * IN_DIM;
        #pragma unroll 8
        for (int k = 0; k < IN_DIM; ++k) s += row[k] * wr[k];
        a[b * H_DIM + j] = fmaxf(s, 0.f);
    }
}

// X (bf16) = concrete_dropout(a, u1, p1)
__global__ void dropx_k(const float* __restrict__ a, const float* __restrict__ u1,
                        const float* __restrict__ pl1, u16* __restrict__ X) {
    int idx_in = blockIdx.x * 256 + threadIdx.x;
    int i = blockIdx.y;
    float p = sigmoidf_(pl1[0]);
    float lp = __logf(p) - log1pf(-p);
    float inv = 1.0f / (1.0f - p);
    size_t gidx = (size_t)i * (B_DIM * H_DIM) + idx_in;
    float u = u1[gidx];
    float z = sigmoidf_((lp + __logf(u) - log1pf(-u)) * TEMP_INV);
    X[gidx] = f2bf(a[idx_in] * (1.0f - z) * inv);
}

// K = o @ fc2_w^T + b; xf = x_pred + K @ residual
__global__ void fc2_corr_k(const float* __restrict__ O, const float* __restrict__ w,
                           const float* __restrict__ bias, const float* __restrict__ resid,
                           const float* __restrict__ xpred, float* __restrict__ xf_ens) {
    int row = blockIdx.x;
    int b = row & (B_DIM - 1);
    __shared__ __align__(16) float orow[OUT1];
    int t = threadIdx.x;
    for (int k = t; k < OUT1; k += 128) orow[k] = O[(size_t)row * OUT1 + k];
    __syncthreads();
    int s = t >> 3, oo = t & 7;
    const float* wr = w + (s * OD + oo) * OUT1;
    float sum = 0.f;
    for (int k = 0; k < OUT1; k += 4) {
        float4 ov = *(const float4*)&orow[k];
        float4 wv = *(const float4*)&wr[k];
        sum += ov.x * wv.x + ov.y * wv.y + ov.z * wv.z + ov.w * wv.w;
    }
    sum += bias[s * OD + oo];
    float v = sum * resid[b * OD + oo];
    v += __shfl_down(v, 4, 8);
    v += __shfl_down(v, 2, 8);
    v += __shfl_down(v, 1, 8);
    if (oo == 0) xf_ens[row * SD + s] = xpred[b * SD + s] + v;
}

__global__ void stats_k(const float* __restrict__ xf_ens, float* __restrict__ out) {
    int b = blockIdx.x;
    __shared__ float xf[S_ENS][SD];
    __shared__ float mean[SD];
    int t = threadIdx.x;
    if (t < S_ENS * SD) {
        int s = t >> 4, k = t & 15;
        xf[s][k] = xf_ens[s * (B_DIM * SD) + b * SD + k];
    }
    __syncthreads();
    if (t < SD) {
        float m = 0.f;
        for (int s = 0; s < S_ENS; ++s) m += xf[s][t];
        m *= (1.0f / S_ENS);
        mean[t] = m;
        out[b * SD + t] = m;
    }
    __syncthreads();
    int i = t >> 4, j = t & 15;
    float p = 0.f;
    for (int s = 0; s < S_ENS; ++s) p += (xf[s][i] - mean[i]) * (xf[s][j] - mean[j]);
    out[B_DIM * SD + b * 256 + t] = p * (1.0f / S_ENS);
}

// fused sumsq for both weight tensors: blockIdx.y selects {fc_in_w, fc1_w}
__global__ void sumsq2_k(const float* __restrict__ w0, int n0,
                         const float* __restrict__ w1, int n1,
                         float* __restrict__ accum) {
    const float* w = blockIdx.y ? w1 : w0;
    int n = blockIdx.y ? n1 : n0;
    float s = 0.f;
    for (int i = blockIdx.x * blockDim.x + threadIdx.x; i < n; i += gridDim.x * blockDim.x) {
        float v = w[i];
        s += v * v;
    }
    #pragma unroll
    for (int d = 32; d >= 1; d >>= 1) s += __shfl_down(s, d, 64);
    __shared__ float red[4];
    int lane = threadIdx.x & 63, wv = threadIdx.x >> 6;
    if (lane == 0) red[wv] = s;
    __syncthreads();
    if (threadIdx.x == 0) atomicAdd(accum + blockIdx.y, red[0] + red[1] + red[2] + red[3]);
}

__global__ void write_reg_k(const float* __restrict__ sums, const float* __restrict__ pl1,
                            const float* __restrict__ pl2, float* __restrict__ out) {
    int t = threadIdx.x;
    float p1 = sigmoidf_(pl1[0]);
    float p2 = sigmoidf_(pl2[0]);
    float ent1 = p1 * logf(p1) + (1.f - p1) * log1pf(-p1);
    float ent2 = p2 * logf(p2) + (1.f - p2) * log1pf(-p2);
    float reg = sums[0] / (1.f - p1) + (float)H_DIM * ent1
              + sums[1] / (1.f - p2) + (float)OUT1 * ent2;
    if (t < S_ENS) out[B_DIM * SD + B_DIM * SD * SD + t] = reg;
}

// ---------------------------------------------------------------------------
extern "C" void kernel_launch(void* const* d_in, const int* in_sizes, int n_in,
                              void* d_out, int out_size, void* d_ws, size_t ws_size,
                              hipStream_t stream) {
    const float* y_t     = (const float*)d_in[0];
    const float* xfp     = (const float*)d_in[1];
    const float* xfpp    = (const float*)d_in[2];
    const float* yprev   = (const float*)d_in[3];
    const float* dxp     = (const float*)d_in[4];
    const float* hprev   = (const float*)d_in[5];
    const float* Fm      = (const float*)d_in[6];
    const float* Hm      = (const float*)d_in[7];
    const float* fc_in_w = (const float*)d_in[8];
    const float* fc_in_b = (const float*)d_in[9];
    const float* W_ih    = (const float*)d_in[10];
    const float* W_hh    = (const float*)d_in[11];
    const float* b_ih    = (const float*)d_in[12];
    const float* b_hh    = (const float*)d_in[13];
    const float* fc1_w   = (const float*)d_in[14];
    const float* fc1_b   = (const float*)d_in[15];
    const float* fc2_w   = (const float*)d_in[16];
    const float* fc2_b   = (const float*)d_in[17];
    const float* pl1     = (const float*)d_in[18];
    const float* pl2     = (const float*)d_in[19];
    const float* u1      = (const float*)d_in[20];
    const float* u2      = (const float*)d_in[21];
    float* out = (float*)d_out;
    char* ws = (char*)d_ws;

    const size_t SZ_W    = (size_t)3 * H_DIM * H_DIM * 2;
    const size_t SZ_MH   = (size_t)M_ROWS * H_DIM * 2;
    size_t off = 0;
    u16* Wihbf  = (u16*)(ws + off); off += SZ_W;
    u16* Whhbf  = (u16*)(ws + off); off += SZ_W;
    u16* Rb     = (u16*)(ws + off); off += SZ_MH;
    u16* Zb     = (u16*)(ws + off); off += SZ_MH;
    u16* Gb     = (u16*)(ws + off); off += SZ_MH;
    u16* Xbf    = (u16*)(ws + off); off += SZ_MH;
    u16* Hpbf   = (u16*)(ws + off); off += SZ_MH;
    u16* Hnbf   = Hpbf;                       // alias: Hpbf dead before phase-B writes
    u16* fc1wbf = (u16*)(ws + off); off += (size_t)OUT1 * H_DIM * 2;
    float* O_buf   = (float*)(ws + off); off += (size_t)M_ROWS * OUT1 * 4;
    float* a_buf   = (float*)(ws + off); off += (size_t)B_DIM * H_DIM * 4;
    float* xf_buf  = (float*)(ws + off); off += (size_t)M_ROWS * SD * 4;
    float* xpred_b = (float*)(ws + off); off += (size_t)B_DIM * SD * 4;
    float* res_b   = (float*)(ws + off); off += (size_t)B_DIM * OD * 4;
    float* sums_b  = (float*)(ws + off); off += 256;

    hipMemsetAsync(sums_b, 0, 2 * sizeof(float), stream);

    prep_fcin_k<<<B_DIM, 256, 0, stream>>>(y_t, xfp, xfpp, yprev, dxp, Fm, Hm,
                                           fc_in_w, fc_in_b, xpred_b, res_b, a_buf);
    dropx_k<<<dim3(B_DIM * H_DIM / 256, S_ENS), 256, 0, stream>>>(a_buf, u1, pl1, Xbf);

    cvt4_k<<<34800, 256, 0, stream>>>(W_ih, Wihbf, W_hh, Whhbf, hprev, Hpbf, fc1_w, fc1wbf);

    // GRU: 128x128 tiles, BK=64 dbuf, v3 2-barrier fat-cluster K-loop.
    gru_gemm_a<<<dim3(M_ROWS / 128, H_DIM / 128, 3), 256, 0, stream>>>(
        Xbf, Hpbf, Wihbf, Whhbf, b_ih, b_hh, Rb, Zb, Gb);
    gru_gemm_b<<<dim3(M_ROWS / 128, H_DIM / 128), 256, 0, stream>>>(
        Xbf, Wihbf, Rb, Zb, Gb, b_ih, hprev, Hnbf);

    fc1_k<<<dim3(OUT1 / 64, M_ROWS / 128), 256, 0, stream>>>(Hnbf, fc1wbf, fc1_b, u2, pl2, O_buf);

    fc2_corr_k<<<M_ROWS, 128, 0, stream>>>(O_buf, fc2_w, fc2_b, res_b, xpred_b, xf_buf);
    stats_k<<<B_DIM, 256, 0, stream>>>(xf_buf, out);
    sumsq2_k<<<dim3(512, 2), 256, 0, stream>>>(fc_in_w, H_DIM * IN_DIM, fc1_w, OUT1 * H_DIM, sums_b);
    write_reg_k<<<1, 64, 0, stream>>>(sums_b, pl1, pl2, out);
}